// Round 2
// baseline (1509.411 us; speedup 1.0000x reference)
//
#include <hip/hip_runtime.h>
#include <hip/hip_bf16.h>
#include <cstdint>

typedef unsigned int  uint;
typedef unsigned short ushort;
using bf16 = __hip_bfloat16;

#define B_     4
#define T_     4096
#define DM     512
#define DI     1024
#define DSTATE 64
#define HD     64
#define NH     16
#define NC     16
#define CHK    256
#define CONVD  1152
#define DPROJ  2192

// ---------- bf16 pack/unpack helpers (bf16 = top 16 bits of fp32) ------------
__device__ inline void unpack8(const uint4 v, float* f) {
  const uint w[4] = {v.x, v.y, v.z, v.w};
#pragma unroll
  for (int i = 0; i < 4; ++i) {
    f[2*i]   = __uint_as_float(w[i] << 16);
    f[2*i+1] = __uint_as_float(w[i] & 0xffff0000u);
  }
}
__device__ inline ushort bfbits(float a) {
  bf16 h = __float2bfloat16(a);
  return *reinterpret_cast<ushort*>(&h);
}
__device__ inline uint pack2(float a, float b) {
  return (uint)bfbits(a) | ((uint)bfbits(b) << 16);
}
__device__ inline uint4 pack8(const float* f) {
  uint4 v;
  v.x = pack2(f[0], f[1]); v.y = pack2(f[2], f[3]);
  v.z = pack2(f[4], f[5]); v.w = pack2(f[6], f[7]);
  return v;
}

// ---------------- GEMM1: zxbcdt = x @ W_in^T, scattered outputs --------------
// A fp32 [M,512], B fp32 [2192,512]; out: z bf16 [M,1024], xbc bf16 [M,1152],
// dtr fp32 [M,16].  Tile 128x128x16.
__global__ __launch_bounds__(256)
void gemm_in(const float* __restrict__ A, const float* __restrict__ Bm,
             bf16* __restrict__ z, bf16* __restrict__ xbc,
             float* __restrict__ dtr) {
  const int M = B_ * T_, N = DPROJ, K = DM;
  __shared__ float As[16][132];
  __shared__ float Bs[16][132];
  const int tid  = threadIdx.x;
  const int bm   = blockIdx.y * 128;
  const int bn   = blockIdx.x * 128;
  const int trow = (tid >> 4) << 3;
  const int tcol = (tid & 15) << 3;

  float acc[8][8];
#pragma unroll
  for (int i = 0; i < 8; ++i)
#pragma unroll
    for (int j = 0; j < 8; ++j) acc[i][j] = 0.f;

  const int lr = tid >> 1;
  const int lk = (tid & 1) << 3;

  for (int k0 = 0; k0 < K; k0 += 16) {
    {
      const float* src = &A[(size_t)(bm + lr) * K + k0 + lk];
      float4 v0 = *reinterpret_cast<const float4*>(src);
      float4 v1 = *reinterpret_cast<const float4*>(src + 4);
      As[lk+0][lr] = v0.x; As[lk+1][lr] = v0.y; As[lk+2][lr] = v0.z; As[lk+3][lr] = v0.w;
      As[lk+4][lr] = v1.x; As[lk+5][lr] = v1.y; As[lk+6][lr] = v1.z; As[lk+7][lr] = v1.w;
    }
    {
      float4 v0 = make_float4(0.f,0.f,0.f,0.f), v1 = v0;
      if (bn + lr < N) {
        const float* src = &Bm[(size_t)(bn + lr) * K + k0 + lk];
        v0 = *reinterpret_cast<const float4*>(src);
        v1 = *reinterpret_cast<const float4*>(src + 4);
      }
      Bs[lk+0][lr] = v0.x; Bs[lk+1][lr] = v0.y; Bs[lk+2][lr] = v0.z; Bs[lk+3][lr] = v0.w;
      Bs[lk+4][lr] = v1.x; Bs[lk+5][lr] = v1.y; Bs[lk+6][lr] = v1.z; Bs[lk+7][lr] = v1.w;
    }
    __syncthreads();
#pragma unroll
    for (int k = 0; k < 16; ++k) {
      float4 a0 = *reinterpret_cast<const float4*>(&As[k][trow]);
      float4 a1 = *reinterpret_cast<const float4*>(&As[k][trow + 4]);
      float4 b0 = *reinterpret_cast<const float4*>(&Bs[k][tcol]);
      float4 b1 = *reinterpret_cast<const float4*>(&Bs[k][tcol + 4]);
      const float av[8] = {a0.x,a0.y,a0.z,a0.w,a1.x,a1.y,a1.z,a1.w};
      const float bv[8] = {b0.x,b0.y,b0.z,b0.w,b1.x,b1.y,b1.z,b1.w};
#pragma unroll
      for (int i = 0; i < 8; ++i)
#pragma unroll
        for (int j = 0; j < 8; ++j) acc[i][j] += av[i] * bv[j];
    }
    __syncthreads();
  }

#pragma unroll
  for (int i = 0; i < 8; ++i) {
    const int row = bm + trow + i;
    const int col = bn + tcol;
    if (bn < DI) {                 // z slice
      *reinterpret_cast<uint4*>(&z[(size_t)row * DI + col]) = pack8(acc[i]);
    } else if (bn < DI + CONVD) {  // xBC slice
      *reinterpret_cast<uint4*>(&xbc[(size_t)row * CONVD + (col - DI)]) = pack8(acc[i]);
    } else if (tcol < 16) {        // dt slice (16 valid cols)
      float* dst = &dtr[(size_t)row * NH + tcol];
      *reinterpret_cast<float4*>(dst)     = make_float4(acc[i][0],acc[i][1],acc[i][2],acc[i][3]);
      *reinterpret_cast<float4*>(dst + 4) = make_float4(acc[i][4],acc[i][5],acc[i][6],acc[i][7]);
    }
  }
}

// ---------------- causal conv(4) + SiLU --------------------------------------
__global__ __launch_bounds__(256)
void conv_silu(const bf16* __restrict__ xbc, const float* __restrict__ cw,
               const float* __restrict__ cb, bf16* __restrict__ xc) {
  const size_t idx = (size_t)blockIdx.x * 256 + threadIdx.x;  // M*CONVD
  const int ch = (int)(idx % CONVD);
  const size_t bt = idx / CONVD;
  const int t = (int)(bt & (T_ - 1));
  float s = cb[ch];
#pragma unroll
  for (int k = 0; k < 4; ++k) {
    const int tt = t - 3 + k;
    if (tt >= 0) s += __bfloat162float(xbc[(bt - 3 + (size_t)k) * CONVD + ch]) * cw[ch * 4 + k];
  }
  const float sig = 1.f / (1.f + __expf(-s));
  xc[idx] = __float2bfloat16(s * sig);
}

// ---------------- dt softplus ------------------------------------------------
__global__ __launch_bounds__(256)
void dt_softplus(const float* __restrict__ dtr, const float* __restrict__ dt_bias,
                 float* __restrict__ dtp) {
  const int idx = blockIdx.x * 256 + threadIdx.x;  // M*NH
  const int h = idx & 15;
  const float v = dtr[idx] + dt_bias[h];
  dtp[idx] = (v > 20.f) ? v : log1pf(expf(v));
}

// ---------------- per-(b,c,h) chunk: cumsum, Y_diag, states ------------------
__global__ __launch_bounds__(256)
void ssd_chunk(const bf16* __restrict__ xc, const float* __restrict__ dtp,
               const float* __restrict__ A_log,
               float* __restrict__ acs_g, float* __restrict__ states,
               bf16* __restrict__ y) {
  const int blk = blockIdx.x;
  const int h = blk & 15;
  const int c = (blk >> 4) & 15;
  const int b = blk >> 8;
  const int tid = threadIdx.x;

  __shared__ float Bt[64][DSTATE];
  __shared__ float Xt[64][HD];
  __shared__ float acs[CHK];

  const size_t row0 = (size_t)b * T_ + (size_t)c * CHK;

  // parallel inclusive cumsum of dt*A over the chunk
  const float Ah = -expf(A_log[h]);
  acs[tid] = dtp[(row0 + tid) * NH + h] * Ah;
  __syncthreads();
#pragma unroll
  for (int off = 1; off < CHK; off <<= 1) {
    const float v = acs[tid];
    const float u = (tid >= off) ? acs[tid - off] : 0.f;
    __syncthreads();
    acs[tid] = v + u;
    __syncthreads();
  }
  const float acs_l = acs[tid];
  const float acs_last = acs[CHK - 1];
  acs_g[(((size_t)b * NH + h) * NC + c) * CHK + tid] = acs_l;

  // this thread's C row (only ever self-read) -> registers
  float Creg[64];
  {
    const uint4* src = reinterpret_cast<const uint4*>(
        &xc[(row0 + tid) * CONVD + DI + DSTATE]);
#pragma unroll
    for (int q = 0; q < 8; ++q) unpack8(src[q], &Creg[q * 8]);
  }

  float accY[HD];
#pragma unroll
  for (int p = 0; p < HD; ++p) accY[p] = 0.f;
  float accS[16];
#pragma unroll
  for (int j = 0; j < 16; ++j) accS[j] = 0.f;

  const int sp  = tid >> 2;
  const int sn0 = (tid & 3) << 4;

  for (int st = 0; st < CHK; st += 64) {
    __syncthreads();
    {
      const int sr = tid >> 2;
      const int c0 = (tid & 3) << 4;
      const size_t rb = (row0 + st + sr) * (size_t)CONVD;
      const float dval = dtp[(row0 + st + sr) * NH + h];
      float f[8];
      const uint4* bsrc = reinterpret_cast<const uint4*>(&xc[rb + DI + c0]);
      uint4 v0 = bsrc[0], v1 = bsrc[1];
      unpack8(v0, f);
#pragma unroll
      for (int j = 0; j < 8; ++j) Bt[sr][c0 + j] = f[j];
      unpack8(v1, f);
#pragma unroll
      for (int j = 0; j < 8; ++j) Bt[sr][c0 + 8 + j] = f[j];
      const uint4* xsrc = reinterpret_cast<const uint4*>(&xc[rb + h * HD + c0]);
      uint4 w0 = xsrc[0], w1 = xsrc[1];
      unpack8(w0, f);
#pragma unroll
      for (int j = 0; j < 8; ++j) Xt[sr][c0 + j] = f[j] * dval;
      unpack8(w1, f);
#pragma unroll
      for (int j = 0; j < 8; ++j) Xt[sr][c0 + 8 + j] = f[j] * dval;
    }
    __syncthreads();

    // Y_diag: thread = output row l=tid; Bt/Xt reads are wave-broadcast
    const int smax = tid - st + 1;
    const int slim = (smax > 64) ? 64 : smax;
    for (int s2 = 0; s2 < slim; ++s2) {
      float dot = 0.f;
#pragma unroll
      for (int n = 0; n < DSTATE; n += 4) {
        float4 bv = *reinterpret_cast<const float4*>(&Bt[s2][n]);
        dot += Creg[n]*bv.x + Creg[n+1]*bv.y + Creg[n+2]*bv.z + Creg[n+3]*bv.w;
      }
      const float w = __expf(acs_l - acs[st + s2]) * dot;
#pragma unroll
      for (int p = 0; p < HD; p += 4) {
        float4 xv = *reinterpret_cast<const float4*>(&Xt[s2][p]);
        accY[p]   += w * xv.x; accY[p+1] += w * xv.y;
        accY[p+2] += w * xv.z; accY[p+3] += w * xv.w;
      }
    }
    // chunk states: thread = (p=tid>>2, 16-col group)
    for (int l2 = 0; l2 < 64; ++l2) {
      const float xv = Xt[l2][sp] * __expf(acs_last - acs[st + l2]);
#pragma unroll
      for (int j = 0; j < 16; j += 4) {
        float4 bv = *reinterpret_cast<const float4*>(&Bt[l2][sn0 + j]);
        accS[j]   += bv.x * xv; accS[j+1] += bv.y * xv;
        accS[j+2] += bv.z * xv; accS[j+3] += bv.w * xv;
      }
    }
  }
  {
    bf16* dst = &y[(row0 + tid) * DI + h * HD];
#pragma unroll
    for (int p = 0; p < HD; p += 8)
      *reinterpret_cast<uint4*>(&dst[p]) = pack8(&accY[p]);
  }
  {
    float* dst = &states[(((size_t)c * B_ + b) * NH + h) * (HD * DSTATE) + sp * DSTATE + sn0];
#pragma unroll
    for (int j = 0; j < 16; j += 4)
      *reinterpret_cast<float4*>(&dst[j]) = make_float4(accS[j], accS[j+1], accS[j+2], accS[j+3]);
  }
}

// ---------------- sequential chunk scan --------------------------------------
__global__ __launch_bounds__(256)
void chunk_scan(const float* __restrict__ acs_g, const float* __restrict__ states,
                float* __restrict__ prev) {
  const int idx = blockIdx.x * 256 + threadIdx.x;  // B*NH*4096
  const int pn = idx & 4095;
  const int h  = (idx >> 12) & 15;
  const int b  = idx >> 16;
  float hst = 0.f;
#pragma unroll
  for (int c = 0; c < NC; ++c) {
    const size_t o = (((size_t)c * B_ + b) * NH + h) * 4096 + pn;
    prev[o] = hst;
    const float dec = __expf(acs_g[(((size_t)b * NH + h) * NC + c) * CHK + CHK - 1]);
    hst = dec * hst + states[o];
  }
}

// ---------------- Y_off + D*xs add -------------------------------------------
__global__ __launch_bounds__(256)
void yoff_add(const bf16* __restrict__ xc, const float* __restrict__ acs_g,
              const float* __restrict__ prev, const float* __restrict__ Dvec,
              bf16* __restrict__ y) {
  const int blk = blockIdx.x;
  const int h = blk & 15, c = (blk >> 4) & 15, b = blk >> 8;
  const int tid = threadIdx.x;
  __shared__ float Pv[HD][DSTATE];
  const size_t row0 = (size_t)b * T_ + (size_t)c * CHK;
  {
    const float* src = &prev[(((size_t)c * B_ + b) * NH + h) * (HD * DSTATE)];
    const int e0 = tid * 16;
    const int p = e0 >> 6, n0 = e0 & 63;
#pragma unroll
    for (int j = 0; j < 16; j += 4) {
      float4 v = *reinterpret_cast<const float4*>(&src[e0 + j]);
      Pv[p][n0+j] = v.x; Pv[p][n0+j+1] = v.y; Pv[p][n0+j+2] = v.z; Pv[p][n0+j+3] = v.w;
    }
  }
  float Creg[64];
  {
    const uint4* src = reinterpret_cast<const uint4*>(
        &xc[(row0 + tid) * CONVD + DI + DSTATE]);
#pragma unroll
    for (int q = 0; q < 8; ++q) unpack8(src[q], &Creg[q * 8]);
  }
  const float e  = __expf(acs_g[(((size_t)b * NH + h) * NC + c) * CHK + tid]);
  const float Dh = Dvec[h];
  const uint4* xsrc = reinterpret_cast<const uint4*>(&xc[(row0 + tid) * CONVD + h * HD]);
  uint4* dst = reinterpret_cast<uint4*>(&y[(row0 + tid) * DI + h * HD]);
  __syncthreads();

#pragma unroll 1
  for (int p0 = 0; p0 < HD; p0 += 8) {
    float yv[8], xs[8];
    unpack8(dst[p0 >> 3], yv);
    unpack8(xsrc[p0 >> 3], xs);
#pragma unroll
    for (int j = 0; j < 8; ++j) {
      float s = 0.f;
#pragma unroll
      for (int n = 0; n < DSTATE; n += 4) {
        float4 pv = *reinterpret_cast<const float4*>(&Pv[p0 + j][n]);
        s += Creg[n]*pv.x + Creg[n+1]*pv.y + Creg[n+2]*pv.z + Creg[n+3]*pv.w;
      }
      yv[j] += e * s + Dh * xs[j];
    }
    dst[p0 >> 3] = pack8(yv);
  }
}

// ---------------- gate (silu(z)) + RMSNorm -----------------------------------
__global__ __launch_bounds__(256)
void gate_rmsnorm(const bf16* __restrict__ z, const float* __restrict__ norm_w,
                  bf16* __restrict__ y) {
  const int row = blockIdx.x;
  const int tid = threadIdx.x;
  const bf16* zrow = &z[(size_t)row * DI];
  bf16* yrow = &y[(size_t)row * DI];
  uint2 yb = *reinterpret_cast<const uint2*>(&yrow[tid * 4]);
  uint2 zb = *reinterpret_cast<const uint2*>(&zrow[tid * 4]);
  float yv[4], zv[4];
  { uint4 t = make_uint4(yb.x, yb.y, 0, 0); float f[8]; unpack8(t, f);
    yv[0]=f[0]; yv[1]=f[1]; yv[2]=f[2]; yv[3]=f[3]; }
  { uint4 t = make_uint4(zb.x, zb.y, 0, 0); float f[8]; unpack8(t, f);
    zv[0]=f[0]; zv[1]=f[1]; zv[2]=f[2]; zv[3]=f[3]; }
  float tq[4];
  float ss = 0.f;
#pragma unroll
  for (int j = 0; j < 4; ++j) {
    const float sil = zv[j] / (1.f + __expf(-zv[j]));
    tq[j] = yv[j] * sil;
    ss += tq[j] * tq[j];
  }
#pragma unroll
  for (int off = 32; off >= 1; off >>= 1) ss += __shfl_down(ss, off);
  __shared__ float red[4];
  if ((tid & 63) == 0) red[tid >> 6] = ss;
  __syncthreads();
  const float tot = red[0] + red[1] + red[2] + red[3];
  const float r = rsqrtf(tot * (1.f / (float)DI) + 1e-5f);
  float4 w = *reinterpret_cast<const float4*>(&norm_w[tid * 4]);
  uint2 ob;
  ob.x = pack2(tq[0] * r * w.x, tq[1] * r * w.y);
  ob.y = pack2(tq[2] * r * w.z, tq[3] * r * w.w);
  *reinterpret_cast<uint2*>(&yrow[tid * 4]) = ob;
}

// ---------------- GEMM2: out = y(bf16) @ W_out^T(fp32) -----------------------
__global__ __launch_bounds__(256)
void gemm_out(const bf16* __restrict__ A, const float* __restrict__ Bm,
              float* __restrict__ C) {
  const int N = DM, K = DI;
  __shared__ float As[16][132];
  __shared__ float Bs[16][132];
  const int tid  = threadIdx.x;
  const int bm   = blockIdx.y * 128;
  const int bn   = blockIdx.x * 128;
  const int trow = (tid >> 4) << 3;
  const int tcol = (tid & 15) << 3;

  float acc[8][8];
#pragma unroll
  for (int i = 0; i < 8; ++i)
#pragma unroll
    for (int j = 0; j < 8; ++j) acc[i][j] = 0.f;

  const int lr = tid >> 1;
  const int lk = (tid & 1) << 3;

  for (int k0 = 0; k0 < K; k0 += 16) {
    {
      const uint4* src = reinterpret_cast<const uint4*>(&A[(size_t)(bm + lr) * K + k0 + lk]);
      float f[8];
      unpack8(src[0], f);
#pragma unroll
      for (int j = 0; j < 8; ++j) As[lk + j][lr] = f[j];
    }
    {
      const float* src = &Bm[(size_t)(bn + lr) * K + k0 + lk];
      float4 v0 = *reinterpret_cast<const float4*>(src);
      float4 v1 = *reinterpret_cast<const float4*>(src + 4);
      Bs[lk+0][lr] = v0.x; Bs[lk+1][lr] = v0.y; Bs[lk+2][lr] = v0.z; Bs[lk+3][lr] = v0.w;
      Bs[lk+4][lr] = v1.x; Bs[lk+5][lr] = v1.y; Bs[lk+6][lr] = v1.z; Bs[lk+7][lr] = v1.w;
    }
    __syncthreads();
#pragma unroll
    for (int k = 0; k < 16; ++k) {
      float4 a0 = *reinterpret_cast<const float4*>(&As[k][trow]);
      float4 a1 = *reinterpret_cast<const float4*>(&As[k][trow + 4]);
      float4 b0 = *reinterpret_cast<const float4*>(&Bs[k][tcol]);
      float4 b1 = *reinterpret_cast<const float4*>(&Bs[k][tcol + 4]);
      const float av[8] = {a0.x,a0.y,a0.z,a0.w,a1.x,a1.y,a1.z,a1.w};
      const float bv[8] = {b0.x,b0.y,b0.z,b0.w,b1.x,b1.y,b1.z,b1.w};
#pragma unroll
      for (int i = 0; i < 8; ++i)
#pragma unroll
        for (int j = 0; j < 8; ++j) acc[i][j] += av[i] * bv[j];
    }
    __syncthreads();
  }
#pragma unroll
  for (int i = 0; i < 8; ++i) {
    float* dst = &C[(size_t)(bm + trow + i) * N + bn + tcol];
    *reinterpret_cast<float4*>(dst)     = make_float4(acc[i][0],acc[i][1],acc[i][2],acc[i][3]);
    *reinterpret_cast<float4*>(dst + 4) = make_float4(acc[i][4],acc[i][5],acc[i][6],acc[i][7]);
  }
}

// ---------------- launcher ---------------------------------------------------
extern "C" void kernel_launch(void* const* d_in, const int* in_sizes, int n_in,
                              void* d_out, int out_size, void* d_ws, size_t ws_size,
                              hipStream_t stream) {
  const float* x       = (const float*)d_in[0];
  const float* W_in    = (const float*)d_in[1];
  const float* conv_w  = (const float*)d_in[2];
  const float* conv_b  = (const float*)d_in[3];
  const float* dt_bias = (const float*)d_in[4];
  const float* A_log   = (const float*)d_in[5];
  const float* Dv      = (const float*)d_in[6];
  const float* norm_w  = (const float*)d_in[7];
  const float* W_out   = (const float*)d_in[8];
  float* out = (float*)d_out;

  char* w0 = (char*)d_ws;
  bf16*  z    = (bf16*) (w0);                    // 33,554,432 B
  bf16*  xbc  = (bf16*) (w0 + 33554432ULL);      // 37,748,736 B (reused as y)
  bf16*  xc   = (bf16*) (w0 + 71303168ULL);      // 37,748,736 B
  float* dtr  = (float*)(w0 + 109051904ULL);     //  1,048,576 B
  float* dtp  = (float*)(w0 + 110100480ULL);     //  1,048,576 B
  float* acs  = (float*)(w0 + 111149056ULL);     //  1,048,576 B
  float* st   = (float*)(w0 + 112197632ULL);     // 16,777,216 B
  float* pv   = (float*)(w0 + 128974848ULL);     // 16,777,216 B
  bf16*  y    = xbc;  // reuse: xbc dead after conv_silu
  // total: 145,752,064 B (~139 MB)

  const int M = B_ * T_;  // 16384

  gemm_in<<<dim3((DPROJ + 127) / 128, M / 128), 256, 0, stream>>>(x, W_in, z, xbc, dtr);
  conv_silu<<<(M * CONVD) / 256, 256, 0, stream>>>(xbc, conv_w, conv_b, xc);
  dt_softplus<<<(M * NH) / 256, 256, 0, stream>>>(dtr, dt_bias, dtp);
  ssd_chunk<<<B_ * NC * NH, 256, 0, stream>>>(xc, dtp, A_log, acs, st, y);
  chunk_scan<<<(B_ * NH * HD * DSTATE) / 256, 256, 0, stream>>>(acs, st, pv);
  yoff_add<<<B_ * NC * NH, 256, 0, stream>>>(xc, acs, pv, Dv, y);
  gate_rmsnorm<<<M, 256, 0, stream>>>(z, norm_w, y);
  gemm_out<<<dim3(DM / 128, M / 128), 256, 0, stream>>>(y, W_out, out);
}

// Round 3
// 380.483 us; speedup vs baseline: 3.9671x; 3.9671x over previous
//
#include <hip/hip_runtime.h>
#include <hip/hip_bf16.h>
#include <cstdint>

typedef unsigned int  uint;
typedef unsigned short ushort;
using bf16 = __hip_bfloat16;

#define B_     4
#define T_     4096
#define DM     512
#define DI     1024
#define DSTATE 64
#define HD     64
#define NH     16
#define NC     16
#define CHK    256
#define CONVD  1152
#define DPROJ  2192

using f32x4 = __attribute__((ext_vector_type(4))) float;
using s16x8 = __attribute__((ext_vector_type(8))) short;

#define MFMA16(a, b, c) __builtin_amdgcn_mfma_f32_16x16x32_bf16((a), (b), (c), 0, 0, 0)

// ---------- bf16 helpers (bf16 = top 16 bits of fp32) ------------------------
__device__ inline void unpack8(const uint4 v, float* f) {
  const uint w[4] = {v.x, v.y, v.z, v.w};
#pragma unroll
  for (int i = 0; i < 4; ++i) {
    f[2*i]   = __uint_as_float(w[i] << 16);
    f[2*i+1] = __uint_as_float(w[i] & 0xffff0000u);
  }
}
__device__ inline void unpack4(const uint2 v, float* f) {
  f[0] = __uint_as_float(v.x << 16); f[1] = __uint_as_float(v.x & 0xffff0000u);
  f[2] = __uint_as_float(v.y << 16); f[3] = __uint_as_float(v.y & 0xffff0000u);
}
__device__ inline ushort bfbits(float a) {
  bf16 h = __float2bfloat16(a);
  return *reinterpret_cast<ushort*>(&h);
}
__device__ inline uint pack2(float a, float b) {
  return (uint)bfbits(a) | ((uint)bfbits(b) << 16);
}
__device__ inline uint4 pack8(const float* f) {
  uint4 v;
  v.x = pack2(f[0], f[1]); v.y = pack2(f[2], f[3]);
  v.z = pack2(f[4], f[5]); v.w = pack2(f[6], f[7]);
  return v;
}

// ---------------- fp32 -> bf16 cast ------------------------------------------
__global__ __launch_bounds__(256)
void cast_bf16(const float* __restrict__ in, short* __restrict__ out, int n8) {
  const int i = blockIdx.x * 256 + threadIdx.x;
  if (i >= n8) return;
  float f[8];
  float4 a = *reinterpret_cast<const float4*>(&in[(size_t)i * 8]);
  float4 b = *reinterpret_cast<const float4*>(&in[(size_t)i * 8 + 4]);
  f[0]=a.x; f[1]=a.y; f[2]=a.z; f[3]=a.w; f[4]=b.x; f[5]=b.y; f[6]=b.z; f[7]=b.w;
  *reinterpret_cast<uint4*>(&out[(size_t)i * 8]) = pack8(f);
}

// ---------------- MFMA GEMM: C[M,N] = A[M,K] (bf16) * B[N,K]^T (bf16) --------
// 128x128 tile, BK=64, 4 waves (2x2), each wave 64x64 via 4x4 MFMA 16x16x32.
// EPI 0: fp32 C [M,512].  EPI 1: scatter z(bf16)/xbc(bf16)/dtr(f32), N=2192.
template<int EPI>
__global__ __launch_bounds__(256)
void gemm_mfma(const short* __restrict__ A, const short* __restrict__ Bw,
               int K, int N, float* __restrict__ Cout,
               short* __restrict__ z, short* __restrict__ xbc,
               float* __restrict__ dtr) {
  __shared__ __align__(16) short As[128][72];
  __shared__ __align__(16) short Bs[128][72];
  const int tid  = threadIdx.x;
  const int lane = tid & 63, w = tid >> 6;
  const int hi = lane >> 4, lo = lane & 15;
  const int wr = w >> 1, wc = w & 1;
  const int bm = blockIdx.y * 128, bn = blockIdx.x * 128;

  f32x4 acc[4][4] = {};  // [lt][nt]

  const int srow = tid >> 3;          // 0..31
  const int scol = (tid & 7) << 3;    // 0..56

  for (int k0 = 0; k0 < K; k0 += 64) {
#pragma unroll
    for (int i = 0; i < 4; ++i) {
      const int r = i * 32 + srow;
      *reinterpret_cast<uint4*>(&As[r][scol]) =
          *reinterpret_cast<const uint4*>(&A[(size_t)(bm + r) * K + k0 + scol]);
      uint4 bv = make_uint4(0, 0, 0, 0);
      if (bn + r < N)
        bv = *reinterpret_cast<const uint4*>(&Bw[(size_t)(bn + r) * K + k0 + scol]);
      *reinterpret_cast<uint4*>(&Bs[r][scol]) = bv;
    }
    __syncthreads();
#pragma unroll
    for (int kb = 0; kb < 2; ++kb) {
      s16x8 af[4], bf[4];
#pragma unroll
      for (int t = 0; t < 4; ++t) {
        af[t] = *reinterpret_cast<const s16x8*>(&As[wr*64 + t*16 + lo][kb*32 + hi*8]);
        bf[t] = *reinterpret_cast<const s16x8*>(&Bs[wc*64 + t*16 + lo][kb*32 + hi*8]);
      }
#pragma unroll
      for (int lt = 0; lt < 4; ++lt)
#pragma unroll
        for (int nt = 0; nt < 4; ++nt)
          acc[lt][nt] = MFMA16(af[lt], bf[nt], acc[lt][nt]);
    }
    __syncthreads();
  }

  // epilogue: D col = lane&15 (+16nt +64wc), row = (lane>>4)*4+reg (+16lt +64wr)
#pragma unroll
  for (int lt = 0; lt < 4; ++lt) {
#pragma unroll
    for (int nt = 0; nt < 4; ++nt) {
      const int cg = bn + wc * 64 + nt * 16 + lo;
#pragma unroll
      for (int r = 0; r < 4; ++r) {
        const int rg = bm + wr * 64 + lt * 16 + hi * 4 + r;
        const float v = acc[lt][nt][r];
        if (EPI == 0) {
          Cout[(size_t)rg * DM + cg] = v;
        } else {
          if (cg < DI) {
            reinterpret_cast<ushort*>(z)[(size_t)rg * DI + cg] = bfbits(v);
          } else if (cg < DI + CONVD) {
            reinterpret_cast<ushort*>(xbc)[(size_t)rg * CONVD + (cg - DI)] = bfbits(v);
          } else if (cg < DPROJ) {
            dtr[(size_t)rg * NH + (cg - DI - CONVD)] = v;
          }
        }
      }
    }
  }
}

// ---------------- causal conv(4) + SiLU (8-wide) -----------------------------
__global__ __launch_bounds__(256)
void conv_silu(const short* __restrict__ xbc, const float* __restrict__ cw,
               const float* __restrict__ cb, short* __restrict__ xc) {
  const int idx = blockIdx.x * 256 + threadIdx.x;  // M * 144
  const int ch0 = (idx % 144) * 8;
  const int bt  = idx / 144;
  const int t   = bt & (T_ - 1);
  float s[8];
#pragma unroll
  for (int j = 0; j < 8; ++j) s[j] = cb[ch0 + j];
#pragma unroll
  for (int k = 0; k < 4; ++k) {
    const int tt = t - 3 + k;
    if (tt >= 0) {
      uint4 v = *reinterpret_cast<const uint4*>(&xbc[(size_t)(bt - 3 + k) * CONVD + ch0]);
      float f[8]; unpack8(v, f);
#pragma unroll
      for (int j = 0; j < 8; ++j) s[j] += f[j] * cw[(ch0 + j) * 4 + k];
    }
  }
#pragma unroll
  for (int j = 0; j < 8; ++j) {
    const float sig = 1.f / (1.f + __expf(-s[j]));
    s[j] = s[j] * sig;
  }
  *reinterpret_cast<uint4*>(&xc[(size_t)bt * CONVD + ch0]) = pack8(s);
}

// ---------------- dt softplus ------------------------------------------------
__global__ __launch_bounds__(256)
void dt_softplus(const float* __restrict__ dtr, const float* __restrict__ dt_bias,
                 float* __restrict__ dtp) {
  const int idx = blockIdx.x * 256 + threadIdx.x;  // M*NH
  const int h = idx & 15;
  const float v = dtr[idx] + dt_bias[h];
  dtp[idx] = (v > 20.f) ? v : log1pf(expf(v));
}

// ---------------- per-(b,c,h) chunk via MFMA ---------------------------------
// wave w owns l-strip [64w,64w+64). Per s-step (64):
//   step1: S^T[s][l] = B*C^T (MFMA, A=B rows, B=C rows from regs)
//   mask/decay in regs -> P(bf16) -> per-wave LDS
//   step2: Y^T[p][l] += X^T * P^T (A=Xt rows, B=P)
//   states[p][n] += (X*decay)^T * B (A=Xd rows, B=Bt)
__global__ __launch_bounds__(256, 2)
void ssd_chunk_mfma(const short* __restrict__ xc, const float* __restrict__ dtp,
                    const float* __restrict__ A_log, const float* __restrict__ Dvec,
                    float* __restrict__ acs_g, float* __restrict__ states,
                    short* __restrict__ y) {
  const int blk = blockIdx.x;
  const int h = blk & 15, c = (blk >> 4) & 15, b = blk >> 8;
  const int tid = threadIdx.x;
  const int lane = tid & 63, w = tid >> 6;
  const int hi = lane >> 4, lo = lane & 15;

  __shared__ __align__(16) float acs[CHK];
  __shared__ __align__(16) short Bsm[64][72];   // B strip [s][n]
  __shared__ __align__(16) short Btm[64][72];   // B^T     [n][s]
  __shared__ __align__(16) short Xtm[64][72];   // (x*dt)^T [p][s]
  __shared__ __align__(16) short Xdm[64][72];   // (x*dt*decay)^T [p][s]
  __shared__ __align__(16) short Pb[4][64][72]; // per-wave P [l][s]

  const size_t row0 = (size_t)b * T_ + (size_t)c * CHK;

  // cumsum of dt*A
  const float Ah = -expf(A_log[h]);
  acs[tid] = dtp[(row0 + tid) * NH + h] * Ah;
  __syncthreads();
#pragma unroll
  for (int off = 1; off < CHK; off <<= 1) {
    const float v = acs[tid];
    const float u = (tid >= off) ? acs[tid - off] : 0.f;
    __syncthreads();
    acs[tid] = v + u;
    __syncthreads();
  }
  acs_g[(((size_t)b * NH + h) * NC + c) * CHK + tid] = acs[tid];
  const float acs_last = acs[CHK - 1];

  // C strip -> registers (A/B-frag layout: row = lane&15, k = (lane>>4)*8+j)
  s16x8 creg[4][2];
#pragma unroll
  for (int lt = 0; lt < 4; ++lt)
#pragma unroll
    for (int kb = 0; kb < 2; ++kb)
      creg[lt][kb] = *reinterpret_cast<const s16x8*>(
          &xc[(row0 + w*64 + lt*16 + lo) * CONVD + DI + DSTATE + kb*32 + hi*8]);

  f32x4 yacc[4][4] = {};   // [pt][lt]
  f32x4 stacc[4]   = {};   // [nt], wave's p-strip 16w..16w+16

  const int sr = tid >> 2;        // staging row s (0..63)
  const int q  = tid & 3;         // 16-col quarter

  for (int ss = 0; ss < 4; ++ss) {
    const int s0 = ss * 64;
    // ---- stage B/Bt/Xt/Xd ----
    {
      const size_t gr = (row0 + s0 + sr) * (size_t)CONVD;
      const float dval = dtp[(row0 + s0 + sr) * NH + h];
      const float ddec = __expf(acs_last - acs[s0 + sr]);
      uint4 b0 = *reinterpret_cast<const uint4*>(&xc[gr + DI + q*16]);
      uint4 b1 = *reinterpret_cast<const uint4*>(&xc[gr + DI + q*16 + 8]);
      *reinterpret_cast<uint4*>(&Bsm[sr][q*16])     = b0;
      *reinterpret_cast<uint4*>(&Bsm[sr][q*16 + 8]) = b1;
      const short* bb0 = reinterpret_cast<const short*>(&b0);
      const short* bb1 = reinterpret_cast<const short*>(&b1);
#pragma unroll
      for (int j = 0; j < 8; ++j) Btm[q*16 + j][sr]     = bb0[j];
#pragma unroll
      for (int j = 0; j < 8; ++j) Btm[q*16 + 8 + j][sr] = bb1[j];
      uint4 x0 = *reinterpret_cast<const uint4*>(&xc[gr + h*HD + q*16]);
      uint4 x1 = *reinterpret_cast<const uint4*>(&xc[gr + h*HD + q*16 + 8]);
      float xf[16]; unpack8(x0, xf); unpack8(x1, xf + 8);
#pragma unroll
      for (int j = 0; j < 16; ++j) {
        const float xd = xf[j] * dval;
        Xtm[q*16 + j][sr] = (short)bfbits(xd);
        Xdm[q*16 + j][sr] = (short)bfbits(xd * ddec);
      }
    }
    __syncthreads();

    if (ss <= w) {   // triangular skip (wave-uniform)
      // ---- step1: S^T = B * C^T ----
      f32x4 sacc[4][4] = {};  // [lt][st]
#pragma unroll
      for (int kb = 0; kb < 2; ++kb) {
        s16x8 bfr[4];
#pragma unroll
        for (int st = 0; st < 4; ++st)
          bfr[st] = *reinterpret_cast<const s16x8*>(&Bsm[st*16 + lo][kb*32 + hi*8]);
#pragma unroll
        for (int lt = 0; lt < 4; ++lt)
#pragma unroll
          for (int st = 0; st < 4; ++st)
            sacc[lt][st] = MFMA16(bfr[st], creg[lt][kb], sacc[lt][st]);
      }
      // ---- mask+decay -> P bf16 -> LDS ----
#pragma unroll
      for (int lt = 0; lt < 4; ++lt) {
        const int l = w*64 + lt*16 + lo;
        const float al = acs[l];
#pragma unroll
        for (int st = 0; st < 4; ++st) {
          float p4[4];
#pragma unroll
          for (int r = 0; r < 4; ++r) {
            const int s = s0 + st*16 + hi*4 + r;
            const float wgt = (s <= l) ? __expf(al - acs[s]) : 0.f;
            p4[r] = sacc[lt][st][r] * wgt;
          }
          uint2 pk; pk.x = pack2(p4[0], p4[1]); pk.y = pack2(p4[2], p4[3]);
          *reinterpret_cast<uint2*>(&Pb[w][lt*16 + lo][st*16 + hi*4]) = pk;
        }
      }
      // ---- step2: Y^T += X^T * P^T ----
#pragma unroll
      for (int kb = 0; kb < 2; ++kb) {
        s16x8 xfr[4], pfr[4];
#pragma unroll
        for (int pt = 0; pt < 4; ++pt)
          xfr[pt] = *reinterpret_cast<const s16x8*>(&Xtm[pt*16 + lo][kb*32 + hi*8]);
#pragma unroll
        for (int lt = 0; lt < 4; ++lt)
          pfr[lt] = *reinterpret_cast<const s16x8*>(&Pb[w][lt*16 + lo][kb*32 + hi*8]);
#pragma unroll
        for (int pt = 0; pt < 4; ++pt)
#pragma unroll
          for (int lt = 0; lt < 4; ++lt)
            yacc[pt][lt] = MFMA16(xfr[pt], pfr[lt], yacc[pt][lt]);
      }
    }
    // ---- states += Xd * B ----
#pragma unroll
    for (int kb = 0; kb < 2; ++kb) {
      s16x8 xdf = *reinterpret_cast<const s16x8*>(&Xdm[w*16 + lo][kb*32 + hi*8]);
#pragma unroll
      for (int nt = 0; nt < 4; ++nt) {
        s16x8 btf = *reinterpret_cast<const s16x8*>(&Btm[nt*16 + lo][kb*32 + hi*8]);
        stacc[nt] = MFMA16(xdf, btf, stacc[nt]);
      }
    }
    __syncthreads();
  }

  // ---- epilogue: Y (+ D*xs) ----  D2: col=l (lane&15), rows=p consecutive
  const float Dh = Dvec[h];
#pragma unroll
  for (int lt = 0; lt < 4; ++lt) {
    const int l = w*64 + lt*16 + lo;
    ushort* yrow = reinterpret_cast<ushort*>(&y[(row0 + l) * DI + h * HD]);
    const short* xrow = &xc[(row0 + l) * CONVD + h * HD];
#pragma unroll
    for (int pt = 0; pt < 4; ++pt) {
      const int p0 = pt*16 + hi*4;
      uint2 xb2 = *reinterpret_cast<const uint2*>(&xrow[p0]);
      float xf[4]; unpack4(xb2, xf);
      float o[4];
#pragma unroll
      for (int r = 0; r < 4; ++r) o[r] = yacc[pt][lt][r] + Dh * xf[r];
      uint2 pk; pk.x = pack2(o[0], o[1]); pk.y = pack2(o[2], o[3]);
      *reinterpret_cast<uint2*>(&yrow[p0]) = pk;
    }
  }
  // ---- states write (fp32) ----
  {
    const size_t sbase = (((size_t)c * B_ + b) * NH + h) * (HD * DSTATE);
#pragma unroll
    for (int nt = 0; nt < 4; ++nt) {
      const int n = nt*16 + lo;
#pragma unroll
      for (int r = 0; r < 4; ++r) {
        const int p = w*16 + hi*4 + r;
        states[sbase + (size_t)p * DSTATE + n] = stacc[nt][r];
      }
    }
  }
}

// ---------------- sequential chunk scan (prev -> bf16) -----------------------
__global__ __launch_bounds__(256)
void chunk_scan(const float* __restrict__ acs_g, const float* __restrict__ st,
                short* __restrict__ pv) {
  const int idx = blockIdx.x * 256 + threadIdx.x;  // B*NH*4096
  const int pn = idx & 4095;
  const int h  = (idx >> 12) & 15;
  const int b  = idx >> 16;
  float hst = 0.f;
#pragma unroll
  for (int c = 0; c < NC; ++c) {
    const size_t o = (((size_t)c * B_ + b) * NH + h) * 4096 + pn;
    reinterpret_cast<ushort*>(pv)[o] = bfbits(hst);
    const float dec = __expf(acs_g[(((size_t)b * NH + h) * NC + c) * CHK + CHK - 1]);
    hst = dec * hst + st[o];
  }
}

// ---------------- Y_off via MFMA: y += exp(acs_l) * C·prev^T -----------------
__global__ __launch_bounds__(256)
void yoff_mfma(const short* __restrict__ xc, const float* __restrict__ acs_g,
               const short* __restrict__ pv, short* __restrict__ y) {
  const int blk = blockIdx.x;
  const int h = blk & 15, c = (blk >> 4) & 15, b = blk >> 8;
  const int tid = threadIdx.x;
  const int lane = tid & 63, w = tid >> 6;
  const int hi = lane >> 4, lo = lane & 15;
  const size_t row0 = (size_t)b * T_ + (size_t)c * CHK;
  const float* ac = &acs_g[(((size_t)b * NH + h) * NC + c) * CHK];
  const short* pvb = &pv[(((size_t)c * B_ + b) * NH + h) * 4096];

  s16x8 creg[4][2];
#pragma unroll
  for (int lt = 0; lt < 4; ++lt)
#pragma unroll
    for (int kb = 0; kb < 2; ++kb)
      creg[lt][kb] = *reinterpret_cast<const s16x8*>(
          &xc[(row0 + w*64 + lt*16 + lo) * CONVD + DI + DSTATE + kb*32 + hi*8]);

  f32x4 acc[4][4] = {};  // [pt][lt]; D[m=p][n=l]
#pragma unroll
  for (int kb = 0; kb < 2; ++kb) {
    s16x8 pf[4];
#pragma unroll
    for (int pt = 0; pt < 4; ++pt)
      pf[pt] = *reinterpret_cast<const s16x8*>(&pvb[(pt*16 + lo) * DSTATE + kb*32 + hi*8]);
#pragma unroll
    for (int pt = 0; pt < 4; ++pt)
#pragma unroll
      for (int lt = 0; lt < 4; ++lt)
        acc[pt][lt] = MFMA16(pf[pt], creg[lt][kb], acc[pt][lt]);
  }
#pragma unroll
  for (int lt = 0; lt < 4; ++lt) {
    const int l = w*64 + lt*16 + lo;
    const float el = __expf(ac[l]);
    ushort* yrow = reinterpret_cast<ushort*>(&y[(row0 + l) * DI + h * HD]);
#pragma unroll
    for (int pt = 0; pt < 4; ++pt) {
      const int p0 = pt*16 + hi*4;
      uint2 cur = *reinterpret_cast<const uint2*>(&yrow[p0]);
      float f[4]; unpack4(cur, f);
#pragma unroll
      for (int r = 0; r < 4; ++r) f[r] += el * acc[pt][lt][r];
      uint2 pk; pk.x = pack2(f[0], f[1]); pk.y = pack2(f[2], f[3]);
      *reinterpret_cast<uint2*>(&yrow[p0]) = pk;
    }
  }
}

// ---------------- gate (silu(z)) + RMSNorm -----------------------------------
__global__ __launch_bounds__(256)
void gate_rmsnorm(const short* __restrict__ z, const float* __restrict__ norm_w,
                  short* __restrict__ y) {
  const int row = blockIdx.x;
  const int tid = threadIdx.x;
  const short* zrow = &z[(size_t)row * DI];
  short* yrow = &y[(size_t)row * DI];
  uint2 yb = *reinterpret_cast<const uint2*>(&yrow[tid * 4]);
  uint2 zb = *reinterpret_cast<const uint2*>(&zrow[tid * 4]);
  float yv[4], zv[4];
  unpack4(yb, yv); unpack4(zb, zv);
  float tq[4];
  float ss = 0.f;
#pragma unroll
  for (int j = 0; j < 4; ++j) {
    const float sil = zv[j] / (1.f + __expf(-zv[j]));
    tq[j] = yv[j] * sil;
    ss += tq[j] * tq[j];
  }
#pragma unroll
  for (int off = 32; off >= 1; off >>= 1) ss += __shfl_down(ss, off);
  __shared__ float red[4];
  if ((tid & 63) == 0) red[tid >> 6] = ss;
  __syncthreads();
  const float tot = red[0] + red[1] + red[2] + red[3];
  const float r = rsqrtf(tot * (1.f / (float)DI) + 1e-5f);
  float4 wv = *reinterpret_cast<const float4*>(&norm_w[tid * 4]);
  uint2 ob;
  ob.x = pack2(tq[0] * r * wv.x, tq[1] * r * wv.y);
  ob.y = pack2(tq[2] * r * wv.z, tq[3] * r * wv.w);
  *reinterpret_cast<uint2*>(&yrow[tid * 4]) = ob;
}

// ---------------- launcher ---------------------------------------------------
extern "C" void kernel_launch(void* const* d_in, const int* in_sizes, int n_in,
                              void* d_out, int out_size, void* d_ws, size_t ws_size,
                              hipStream_t stream) {
  const float* x       = (const float*)d_in[0];
  const float* W_in    = (const float*)d_in[1];
  const float* conv_w  = (const float*)d_in[2];
  const float* conv_b  = (const float*)d_in[3];
  const float* dt_bias = (const float*)d_in[4];
  const float* A_log   = (const float*)d_in[5];
  const float* Dv      = (const float*)d_in[6];
  const float* norm_w  = (const float*)d_in[7];
  const float* W_out   = (const float*)d_in[8];
  float* out = (float*)d_out;

  char* w0 = (char*)d_ws;
  short* z    = (short*)(w0);                    // 33,554,432 B
  short* xbc  = (short*)(w0 + 33554432ULL);      // 37,748,736 B (reused as y)
  short* xc   = (short*)(w0 + 71303168ULL);      // 37,748,736 B (xb aliases base)
  short* wob  = (short*)(w0 + 109051904ULL);     //  1,048,576 B
  float* dtr  = (float*)(w0 + 110100480ULL);     //  1,048,576 B
  float* dtp  = (float*)(w0 + 111149056ULL);     //  1,048,576 B
  float* acs  = (float*)(w0 + 112197632ULL);     //  1,048,576 B
  float* st   = (float*)(w0 + 113246208ULL);     // 16,777,216 B (wb aliases base)
  short* pv   = (short*)(w0 + 130023424ULL);     //  8,388,608 B
  short* xb   = xc;   // bf16 x: dead before conv writes xc
  short* wb   = (short*)st;  // bf16 W_in: dead before ssd writes st
  short* y    = xbc;  // y reuses xbc after conv consumes it
  // total: 138,412,032 B

  const int M = B_ * T_;  // 16384

  cast_bf16<<<(M * DM / 8 + 255) / 256, 256, 0, stream>>>(x, xb, M * DM / 8);
  cast_bf16<<<(DPROJ * DM / 8 + 255) / 256, 256, 0, stream>>>(W_in, wb, DPROJ * DM / 8);
  cast_bf16<<<(DM * DI / 8 + 255) / 256, 256, 0, stream>>>(W_out, wob, DM * DI / 8);

  gemm_mfma<1><<<dim3((DPROJ + 127) / 128, M / 128), 256, 0, stream>>>(
      xb, wb, DM, DPROJ, nullptr, z, xbc, dtr);
  conv_silu<<<(M * 144) / 256, 256, 0, stream>>>(xbc, conv_w, conv_b, xc);
  dt_softplus<<<(M * NH) / 256, 256, 0, stream>>>(dtr, dt_bias, dtp);
  ssd_chunk_mfma<<<B_ * NC * NH, 256, 0, stream>>>(xc, dtp, A_log, Dv, acs, st, y);
  chunk_scan<<<(B_ * NH * HD * DSTATE) / 256, 256, 0, stream>>>(acs, st, pv);
  yoff_mfma<<<B_ * NC * NH, 256, 0, stream>>>(xc, acs, pv, y);
  gate_rmsnorm<<<M, 256, 0, stream>>>(z, norm_w, y);
  gemm_mfma<0><<<dim3(DM / 128, M / 128), 256, 0, stream>>>(
      y, wob, DI, DM, out, nullptr, nullptr, nullptr);
}

// Round 4
// 260.845 us; speedup vs baseline: 5.7866x; 1.4587x over previous
//
#include <hip/hip_runtime.h>
#include <hip/hip_bf16.h>
#include <cstdint>

typedef unsigned int  uint;
typedef unsigned short ushort;
using bf16 = __hip_bfloat16;

#define B_     4
#define T_     4096
#define DM     512
#define DI     1024
#define DSTATE 64
#define HD     64
#define NH     16
#define NC     16
#define CHK    256
#define CONVD  1152
#define DPROJ  2192

using f32x4 = __attribute__((ext_vector_type(4))) float;
using s16x8 = __attribute__((ext_vector_type(8))) short;

#define MFMA16(a, b, c) __builtin_amdgcn_mfma_f32_16x16x32_bf16((a), (b), (c), 0, 0, 0)

// ---------- bf16 helpers (bf16 = top 16 bits of fp32) ------------------------
__device__ inline void unpack8(const uint4 v, float* f) {
  const uint w[4] = {v.x, v.y, v.z, v.w};
#pragma unroll
  for (int i = 0; i < 4; ++i) {
    f[2*i]   = __uint_as_float(w[i] << 16);
    f[2*i+1] = __uint_as_float(w[i] & 0xffff0000u);
  }
}
__device__ inline void unpack4(const uint2 v, float* f) {
  f[0] = __uint_as_float(v.x << 16); f[1] = __uint_as_float(v.x & 0xffff0000u);
  f[2] = __uint_as_float(v.y << 16); f[3] = __uint_as_float(v.y & 0xffff0000u);
}
__device__ inline ushort bfbits(float a) {
  bf16 h = __float2bfloat16(a);
  return *reinterpret_cast<ushort*>(&h);
}
__device__ inline uint pack2(float a, float b) {
  return (uint)bfbits(a) | ((uint)bfbits(b) << 16);
}
__device__ inline uint4 pack8(const float* f) {
  uint4 v;
  v.x = pack2(f[0], f[1]); v.y = pack2(f[2], f[3]);
  v.z = pack2(f[4], f[5]); v.w = pack2(f[6], f[7]);
  return v;
}

// ---------------- fp32 -> bf16 cast ------------------------------------------
__global__ __launch_bounds__(256)
void cast_bf16(const float* __restrict__ in, short* __restrict__ out, int n8) {
  const int i = blockIdx.x * 256 + threadIdx.x;
  if (i >= n8) return;
  float f[8];
  float4 a = *reinterpret_cast<const float4*>(&in[(size_t)i * 8]);
  float4 b = *reinterpret_cast<const float4*>(&in[(size_t)i * 8 + 4]);
  f[0]=a.x; f[1]=a.y; f[2]=a.z; f[3]=a.w; f[4]=b.x; f[5]=b.y; f[6]=b.z; f[7]=b.w;
  *reinterpret_cast<uint4*>(&out[(size_t)i * 8]) = pack8(f);
}

// ---------------- MFMA GEMM: C[M,N] = A[M,K] (bf16) * B[N,K]^T (bf16) --------
// 128x128 tile, BK=64, 4 waves (2x2), each wave 64x64 via 4x4 MFMA 16x16x32.
// EPI 0: fp32 C [M,512].  EPI 1: scatter z(bf16)/xbc(bf16) via LDS-transpose
//        (coalesced uint4 stores) + dtr(f32) direct from regs.
template<int EPI>
__global__ __launch_bounds__(256)
void gemm_mfma(const short* __restrict__ A, const short* __restrict__ Bw,
               int K, int N, float* __restrict__ Cout,
               short* __restrict__ z, short* __restrict__ xbc,
               float* __restrict__ dtr) {
  __shared__ __align__(16) short smem[2][128][72];
  short (*As)[72] = smem[0];
  short (*Bs)[72] = smem[1];
  const int tid  = threadIdx.x;
  const int lane = tid & 63, w = tid >> 6;
  const int hi = lane >> 4, lo = lane & 15;
  const int wr = w >> 1, wc = w & 1;
  const int bm = blockIdx.y * 128, bn = blockIdx.x * 128;

  f32x4 acc[4][4] = {};  // [lt][nt]

  const int srow = tid >> 3;          // 0..31
  const int scol = (tid & 7) << 3;    // 0..56

  for (int k0 = 0; k0 < K; k0 += 64) {
#pragma unroll
    for (int i = 0; i < 4; ++i) {
      const int r = i * 32 + srow;
      *reinterpret_cast<uint4*>(&As[r][scol]) =
          *reinterpret_cast<const uint4*>(&A[(size_t)(bm + r) * K + k0 + scol]);
      uint4 bv = make_uint4(0, 0, 0, 0);
      if (bn + r < N)
        bv = *reinterpret_cast<const uint4*>(&Bw[(size_t)(bn + r) * K + k0 + scol]);
      *reinterpret_cast<uint4*>(&Bs[r][scol]) = bv;
    }
    __syncthreads();
#pragma unroll
    for (int kb = 0; kb < 2; ++kb) {
      s16x8 af[4], bf[4];
#pragma unroll
      for (int t = 0; t < 4; ++t) {
        af[t] = *reinterpret_cast<const s16x8*>(&As[wr*64 + t*16 + lo][kb*32 + hi*8]);
        bf[t] = *reinterpret_cast<const s16x8*>(&Bs[wc*64 + t*16 + lo][kb*32 + hi*8]);
      }
#pragma unroll
      for (int lt = 0; lt < 4; ++lt)
#pragma unroll
        for (int nt = 0; nt < 4; ++nt)
          acc[lt][nt] = MFMA16(af[lt], bf[nt], acc[lt][nt]);
    }
    __syncthreads();
  }

  // D frag: col = lane&15 (+16nt +64wc), row = (lane>>4)*4+reg (+16lt +64wr)
  if (EPI == 0) {
#pragma unroll
    for (int lt = 0; lt < 4; ++lt)
#pragma unroll
      for (int nt = 0; nt < 4; ++nt) {
        const int cg = bn + wc * 64 + nt * 16 + lo;
#pragma unroll
        for (int r = 0; r < 4; ++r) {
          const int rg = bm + wr * 64 + lt * 16 + hi * 4 + r;
          Cout[(size_t)rg * DM + cg] = acc[lt][nt][r];
        }
      }
  } else {
    // dt columns (fp32) straight from registers
    if (bn + 64 >= DI + CONVD) {
#pragma unroll
      for (int lt = 0; lt < 4; ++lt)
#pragma unroll
        for (int nt = 0; nt < 4; ++nt) {
          const int cg = bn + wc * 64 + nt * 16 + lo;
          if (cg >= DI + CONVD && cg < DPROJ) {
#pragma unroll
            for (int r = 0; r < 4; ++r) {
              const int rg = bm + wr * 64 + lt * 16 + hi * 4 + r;
              dtr[(size_t)rg * NH + (cg - DI - CONVD)] = acc[lt][nt][r];
            }
          }
        }
    }
    // bf16 z/xBC via LDS transpose -> coalesced uint4 stores
    ushort (*tile)[136] = reinterpret_cast<ushort(*)[136]>(&smem[0][0][0]);
    __syncthreads();   // staging LDS dead; safe to overwrite
#pragma unroll
    for (int lt = 0; lt < 4; ++lt)
#pragma unroll
      for (int nt = 0; nt < 4; ++nt) {
        const int cl = wc * 64 + nt * 16 + lo;
#pragma unroll
        for (int r = 0; r < 4; ++r)
          tile[wr * 64 + lt * 16 + hi * 4 + r][cl] = bfbits(acc[lt][nt][r]);
      }
    __syncthreads();
#pragma unroll
    for (int it = 0; it < 8; ++it) {
      const int unit = it * 256 + tid;      // 2048 units = 128 rows x 16 col8s
      const int row = unit >> 4;
      const int c8  = (unit & 15) << 3;
      const int cg  = bn + c8;
      const int rg  = bm + row;
      if (cg >= DI + CONVD) continue;
      uint4 v = *reinterpret_cast<const uint4*>(&tile[row][c8]);
      if (cg < DI)
        *reinterpret_cast<uint4*>(&reinterpret_cast<ushort*>(z)[(size_t)rg * DI + cg]) = v;
      else
        *reinterpret_cast<uint4*>(&reinterpret_cast<ushort*>(xbc)[(size_t)rg * CONVD + (cg - DI)]) = v;
    }
  }
}

// ---------------- causal conv(4) + SiLU --------------------------------------
// thread <-> (channel pair, 8-timestep block): coalesced loads/stores,
// vectorized float4 weight loads, taps reused in registers.
__global__ __launch_bounds__(256)
void conv_silu(const short* __restrict__ xbc, const float* __restrict__ cw,
               const float* __restrict__ cb, short* __restrict__ xc) {
  const int idx = blockIdx.x * 256 + threadIdx.x;  // (M/8) * 576
  const int cp = idx % 576;
  const int tb = idx / 576;
  const int ch = cp * 2;
  const int b  = tb >> 9;                 // T_/8 = 512 blocks per batch
  const int t0 = (tb & 511) << 3;
  const long base = ((long)b * T_ + t0) * CONVD + ch;

  const float4 wa = *reinterpret_cast<const float4*>(&cw[ch * 4]);
  const float4 wb = *reinterpret_cast<const float4*>(&cw[ch * 4 + 4]);
  const float ba = cb[ch], bb = cb[ch + 1];

  float va[11], vb[11];
#pragma unroll
  for (int i = 0; i < 11; ++i) {
    const int t = t0 - 3 + i;
    if (t >= 0) {
      const uint u = *reinterpret_cast<const uint*>(&xbc[base + (long)(i - 3) * CONVD]);
      va[i] = __uint_as_float(u << 16);
      vb[i] = __uint_as_float(u & 0xffff0000u);
    } else { va[i] = 0.f; vb[i] = 0.f; }
  }
#pragma unroll
  for (int j = 0; j < 8; ++j) {
    float sa = ba + va[j]*wa.x + va[j+1]*wa.y + va[j+2]*wa.z + va[j+3]*wa.w;
    float sb = bb + vb[j]*wb.x + vb[j+1]*wb.y + vb[j+2]*wb.z + vb[j+3]*wb.w;
    sa = sa / (1.f + __expf(-sa));
    sb = sb / (1.f + __expf(-sb));
    *reinterpret_cast<uint*>(&xc[base + (long)j * CONVD]) = pack2(sa, sb);
  }
}

// ---------------- dt softplus ------------------------------------------------
__global__ __launch_bounds__(256)
void dt_softplus(const float* __restrict__ dtr, const float* __restrict__ dt_bias,
                 float* __restrict__ dtp) {
  const int idx = blockIdx.x * 256 + threadIdx.x;  // M*NH
  const int h = idx & 15;
  const float v = dtr[idx] + dt_bias[h];
  dtp[idx] = (v > 20.f) ? v : log1pf(expf(v));
}

// ---------------- per-(b,c,h) chunk via MFMA ---------------------------------
__global__ __launch_bounds__(256, 2)
void ssd_chunk_mfma(const short* __restrict__ xc, const float* __restrict__ dtp,
                    const float* __restrict__ A_log, const float* __restrict__ Dvec,
                    float* __restrict__ acs_g, float* __restrict__ states,
                    short* __restrict__ y) {
  const int blk = blockIdx.x;
  const int h = blk & 15, c = (blk >> 4) & 15, b = blk >> 8;
  const int tid = threadIdx.x;
  const int lane = tid & 63, w = tid >> 6;
  const int hi = lane >> 4, lo = lane & 15;

  __shared__ __align__(16) float acs[CHK];
  __shared__ __align__(16) short Bsm[64][72];   // B strip [s][n]
  __shared__ __align__(16) short Btm[64][72];   // B^T     [n][s]
  __shared__ __align__(16) short Xtm[64][72];   // (x*dt)^T [p][s]
  __shared__ __align__(16) short Xdm[64][72];   // (x*dt*decay)^T [p][s]
  __shared__ __align__(16) short Pb[4][64][72]; // per-wave P [l][s]

  const size_t row0 = (size_t)b * T_ + (size_t)c * CHK;

  // cumsum of dt*A
  const float Ah = -expf(A_log[h]);
  acs[tid] = dtp[(row0 + tid) * NH + h] * Ah;
  __syncthreads();
#pragma unroll
  for (int off = 1; off < CHK; off <<= 1) {
    const float v = acs[tid];
    const float u = (tid >= off) ? acs[tid - off] : 0.f;
    __syncthreads();
    acs[tid] = v + u;
    __syncthreads();
  }
  acs_g[(((size_t)b * NH + h) * NC + c) * CHK + tid] = acs[tid];
  const float acs_last = acs[CHK - 1];

  // C strip -> registers (frag layout: row = lane&15, k = (lane>>4)*8+j)
  s16x8 creg[4][2];
#pragma unroll
  for (int lt = 0; lt < 4; ++lt)
#pragma unroll
    for (int kb = 0; kb < 2; ++kb)
      creg[lt][kb] = *reinterpret_cast<const s16x8*>(
          &xc[(row0 + w*64 + lt*16 + lo) * CONVD + DI + DSTATE + kb*32 + hi*8]);

  f32x4 yacc[4][4] = {};   // [pt][lt]
  f32x4 stacc[4]   = {};   // [nt], wave's p-strip 16w..16w+16

  const int sr = tid >> 2;        // staging row s (0..63)
  const int q  = tid & 3;         // 16-col quarter

  for (int ss = 0; ss < 4; ++ss) {
    const int s0 = ss * 64;
    // ---- stage B/Bt/Xt/Xd ----
    {
      const size_t gr = (row0 + s0 + sr) * (size_t)CONVD;
      const float dval = dtp[(row0 + s0 + sr) * NH + h];
      const float ddec = __expf(acs_last - acs[s0 + sr]);
      uint4 b0 = *reinterpret_cast<const uint4*>(&xc[gr + DI + q*16]);
      uint4 b1 = *reinterpret_cast<const uint4*>(&xc[gr + DI + q*16 + 8]);
      *reinterpret_cast<uint4*>(&Bsm[sr][q*16])     = b0;
      *reinterpret_cast<uint4*>(&Bsm[sr][q*16 + 8]) = b1;
      const short* bb0 = reinterpret_cast<const short*>(&b0);
      const short* bb1 = reinterpret_cast<const short*>(&b1);
#pragma unroll
      for (int j = 0; j < 8; ++j) Btm[q*16 + j][sr]     = bb0[j];
#pragma unroll
      for (int j = 0; j < 8; ++j) Btm[q*16 + 8 + j][sr] = bb1[j];
      uint4 x0 = *reinterpret_cast<const uint4*>(&xc[gr + h*HD + q*16]);
      uint4 x1 = *reinterpret_cast<const uint4*>(&xc[gr + h*HD + q*16 + 8]);
      float xf[16]; unpack8(x0, xf); unpack8(x1, xf + 8);
#pragma unroll
      for (int j = 0; j < 16; ++j) {
        const float xd = xf[j] * dval;
        Xtm[q*16 + j][sr] = (short)bfbits(xd);
        Xdm[q*16 + j][sr] = (short)bfbits(xd * ddec);
      }
    }
    __syncthreads();

    if (ss <= w) {   // triangular skip (wave-uniform)
      // ---- step1: S^T = B * C^T ----
      f32x4 sacc[4][4] = {};  // [lt][st]
#pragma unroll
      for (int kb = 0; kb < 2; ++kb) {
        s16x8 bfr[4];
#pragma unroll
        for (int st = 0; st < 4; ++st)
          bfr[st] = *reinterpret_cast<const s16x8*>(&Bsm[st*16 + lo][kb*32 + hi*8]);
#pragma unroll
        for (int lt = 0; lt < 4; ++lt)
#pragma unroll
          for (int st = 0; st < 4; ++st)
            sacc[lt][st] = MFMA16(bfr[st], creg[lt][kb], sacc[lt][st]);
      }
      // ---- mask+decay -> P bf16 -> LDS ----
#pragma unroll
      for (int lt = 0; lt < 4; ++lt) {
        const int l = w*64 + lt*16 + lo;
        const float al = acs[l];
#pragma unroll
        for (int st = 0; st < 4; ++st) {
          float p4[4];
#pragma unroll
          for (int r = 0; r < 4; ++r) {
            const int s = s0 + st*16 + hi*4 + r;
            const float wgt = (s <= l) ? __expf(al - acs[s]) : 0.f;
            p4[r] = sacc[lt][st][r] * wgt;
          }
          uint2 pk; pk.x = pack2(p4[0], p4[1]); pk.y = pack2(p4[2], p4[3]);
          *reinterpret_cast<uint2*>(&Pb[w][lt*16 + lo][st*16 + hi*4]) = pk;
        }
      }
      // ---- step2: Y^T += X^T * P^T ----
#pragma unroll
      for (int kb = 0; kb < 2; ++kb) {
        s16x8 xfr[4], pfr[4];
#pragma unroll
        for (int pt = 0; pt < 4; ++pt)
          xfr[pt] = *reinterpret_cast<const s16x8*>(&Xtm[pt*16 + lo][kb*32 + hi*8]);
#pragma unroll
        for (int lt = 0; lt < 4; ++lt)
          pfr[lt] = *reinterpret_cast<const s16x8*>(&Pb[w][lt*16 + lo][kb*32 + hi*8]);
#pragma unroll
        for (int pt = 0; pt < 4; ++pt)
#pragma unroll
          for (int lt = 0; lt < 4; ++lt)
            yacc[pt][lt] = MFMA16(xfr[pt], pfr[lt], yacc[pt][lt]);
      }
    }
    // ---- states += Xd * B ----
#pragma unroll
    for (int kb = 0; kb < 2; ++kb) {
      s16x8 xdf = *reinterpret_cast<const s16x8*>(&Xdm[w*16 + lo][kb*32 + hi*8]);
#pragma unroll
      for (int nt = 0; nt < 4; ++nt) {
        s16x8 btf = *reinterpret_cast<const s16x8*>(&Btm[nt*16 + lo][kb*32 + hi*8]);
        stacc[nt] = MFMA16(xdf, btf, stacc[nt]);
      }
    }
    __syncthreads();
  }

  // ---- epilogue: Y (+ D*xs) ----
  const float Dh = Dvec[h];
#pragma unroll
  for (int lt = 0; lt < 4; ++lt) {
    const int l = w*64 + lt*16 + lo;
    ushort* yrow = reinterpret_cast<ushort*>(&y[(row0 + l) * DI + h * HD]);
    const short* xrow = &xc[(row0 + l) * CONVD + h * HD];
#pragma unroll
    for (int pt = 0; pt < 4; ++pt) {
      const int p0 = pt*16 + hi*4;
      uint2 xb2 = *reinterpret_cast<const uint2*>(&xrow[p0]);
      float xf[4]; unpack4(xb2, xf);
      float o[4];
#pragma unroll
      for (int r = 0; r < 4; ++r) o[r] = yacc[pt][lt][r] + Dh * xf[r];
      uint2 pk; pk.x = pack2(o[0], o[1]); pk.y = pack2(o[2], o[3]);
      *reinterpret_cast<uint2*>(&yrow[p0]) = pk;
    }
  }
  // ---- states write (fp32) ----
  {
    const size_t sbase = (((size_t)c * B_ + b) * NH + h) * (HD * DSTATE);
#pragma unroll
    for (int nt = 0; nt < 4; ++nt) {
      const int n = nt*16 + lo;
#pragma unroll
      for (int r = 0; r < 4; ++r) {
        const int p = w*16 + hi*4 + r;
        states[sbase + (size_t)p * DSTATE + n] = stacc[nt][r];
      }
    }
  }
}

// ---------------- sequential chunk scan (prev -> bf16) -----------------------
__global__ __launch_bounds__(256)
void chunk_scan(const float* __restrict__ acs_g, const float* __restrict__ st,
                short* __restrict__ pv) {
  const int idx = blockIdx.x * 256 + threadIdx.x;  // B*NH*4096
  const int pn = idx & 4095;
  const int h  = (idx >> 12) & 15;
  const int b  = idx >> 16;
  float hst = 0.f;
#pragma unroll
  for (int c = 0; c < NC; ++c) {
    const size_t o = (((size_t)c * B_ + b) * NH + h) * 4096 + pn;
    reinterpret_cast<ushort*>(pv)[o] = bfbits(hst);
    const float dec = __expf(acs_g[(((size_t)b * NH + h) * NC + c) * CHK + CHK - 1]);
    hst = dec * hst + st[o];
  }
}

// ---------------- Y_off via MFMA: y += exp(acs_l) * C·prev^T -----------------
__global__ __launch_bounds__(256)
void yoff_mfma(const short* __restrict__ xc, const float* __restrict__ acs_g,
               const short* __restrict__ pv, short* __restrict__ y) {
  const int blk = blockIdx.x;
  const int h = blk & 15, c = (blk >> 4) & 15, b = blk >> 8;
  const int tid = threadIdx.x;
  const int lane = tid & 63, w = tid >> 6;
  const int hi = lane >> 4, lo = lane & 15;
  const size_t row0 = (size_t)b * T_ + (size_t)c * CHK;
  const float* ac = &acs_g[(((size_t)b * NH + h) * NC + c) * CHK];
  const short* pvb = &pv[(((size_t)c * B_ + b) * NH + h) * 4096];

  s16x8 creg[4][2];
#pragma unroll
  for (int lt = 0; lt < 4; ++lt)
#pragma unroll
    for (int kb = 0; kb < 2; ++kb)
      creg[lt][kb] = *reinterpret_cast<const s16x8*>(
          &xc[(row0 + w*64 + lt*16 + lo) * CONVD + DI + DSTATE + kb*32 + hi*8]);

  f32x4 acc[4][4] = {};  // [pt][lt]; D[m=p][n=l]
#pragma unroll
  for (int kb = 0; kb < 2; ++kb) {
    s16x8 pf[4];
#pragma unroll
    for (int pt = 0; pt < 4; ++pt)
      pf[pt] = *reinterpret_cast<const s16x8*>(&pvb[(pt*16 + lo) * DSTATE + kb*32 + hi*8]);
#pragma unroll
    for (int pt = 0; pt < 4; ++pt)
#pragma unroll
      for (int lt = 0; lt < 4; ++lt)
        acc[pt][lt] = MFMA16(pf[pt], creg[lt][kb], acc[pt][lt]);
  }
#pragma unroll
  for (int lt = 0; lt < 4; ++lt) {
    const int l = w*64 + lt*16 + lo;
    const float el = __expf(ac[l]);
    ushort* yrow = reinterpret_cast<ushort*>(&y[(row0 + l) * DI + h * HD]);
#pragma unroll
    for (int pt = 0; pt < 4; ++pt) {
      const int p0 = pt*16 + hi*4;
      uint2 cur = *reinterpret_cast<const uint2*>(&yrow[p0]);
      float f[4]; unpack4(cur, f);
#pragma unroll
      for (int r = 0; r < 4; ++r) f[r] += el * acc[pt][lt][r];
      uint2 pk; pk.x = pack2(f[0], f[1]); pk.y = pack2(f[2], f[3]);
      *reinterpret_cast<uint2*>(&yrow[p0]) = pk;
    }
  }
}

// ---------------- gate (silu(z)) + RMSNorm -----------------------------------
__global__ __launch_bounds__(256)
void gate_rmsnorm(const short* __restrict__ z, const float* __restrict__ norm_w,
                  short* __restrict__ y) {
  const int row = blockIdx.x;
  const int tid = threadIdx.x;
  const short* zrow = &z[(size_t)row * DI];
  short* yrow = &y[(size_t)row * DI];
  uint2 yb = *reinterpret_cast<const uint2*>(&yrow[tid * 4]);
  uint2 zb = *reinterpret_cast<const uint2*>(&zrow[tid * 4]);
  float yv[4], zv[4];
  unpack4(yb, yv); unpack4(zb, zv);
  float tq[4];
  float ss = 0.f;
#pragma unroll
  for (int j = 0; j < 4; ++j) {
    const float sil = zv[j] / (1.f + __expf(-zv[j]));
    tq[j] = yv[j] * sil;
    ss += tq[j] * tq[j];
  }
#pragma unroll
  for (int off = 32; off >= 1; off >>= 1) ss += __shfl_down(ss, off);
  __shared__ float red[4];
  if ((tid & 63) == 0) red[tid >> 6] = ss;
  __syncthreads();
  const float tot = red[0] + red[1] + red[2] + red[3];
  const float r = rsqrtf(tot * (1.f / (float)DI) + 1e-5f);
  float4 wv = *reinterpret_cast<const float4*>(&norm_w[tid * 4]);
  uint2 ob;
  ob.x = pack2(tq[0] * r * wv.x, tq[1] * r * wv.y);
  ob.y = pack2(tq[2] * r * wv.z, tq[3] * r * wv.w);
  *reinterpret_cast<uint2*>(&yrow[tid * 4]) = ob;
}

// ---------------- launcher ---------------------------------------------------
extern "C" void kernel_launch(void* const* d_in, const int* in_sizes, int n_in,
                              void* d_out, int out_size, void* d_ws, size_t ws_size,
                              hipStream_t stream) {
  const float* x       = (const float*)d_in[0];
  const float* W_in    = (const float*)d_in[1];
  const float* conv_w  = (const float*)d_in[2];
  const float* conv_b  = (const float*)d_in[3];
  const float* dt_bias = (const float*)d_in[4];
  const float* A_log   = (const float*)d_in[5];
  const float* Dv      = (const float*)d_in[6];
  const float* norm_w  = (const float*)d_in[7];
  const float* W_out   = (const float*)d_in[8];
  float* out = (float*)d_out;

  char* w0 = (char*)d_ws;
  short* z    = (short*)(w0);                    // 33,554,432 B
  short* xbc  = (short*)(w0 + 33554432ULL);      // 37,748,736 B (reused as y)
  short* xc   = (short*)(w0 + 71303168ULL);      // 37,748,736 B (xb aliases base)
  short* wob  = (short*)(w0 + 109051904ULL);     //  1,048,576 B
  float* dtr  = (float*)(w0 + 110100480ULL);     //  1,048,576 B
  float* dtp  = (float*)(w0 + 111149056ULL);     //  1,048,576 B
  float* acs  = (float*)(w0 + 112197632ULL);     //  1,048,576 B
  float* st   = (float*)(w0 + 113246208ULL);     // 16,777,216 B (wb aliases base)
  short* pv   = (short*)(w0 + 130023424ULL);     //  8,388,608 B
  short* xb   = xc;          // bf16 x: dead before conv writes xc
  short* wb   = (short*)st;  // bf16 W_in: dead before ssd writes st
  short* y    = xbc;         // y reuses xbc after conv consumes it
  // total: 138,412,032 B

  const int M = B_ * T_;  // 16384

  cast_bf16<<<(M * DM / 8 + 255) / 256, 256, 0, stream>>>(x, xb, M * DM / 8);
  cast_bf16<<<(DPROJ * DM / 8 + 255) / 256, 256, 0, stream>>>(W_in, wb, DPROJ * DM / 8);
  cast_bf16<<<(DM * DI / 8 + 255) / 256, 256, 0, stream>>>(W_out, wob, DM * DI / 8);

  gemm_mfma<1><<<dim3((DPROJ + 127) / 128, M / 128), 256, 0, stream>>>(
      xb, wb, DM, DPROJ, nullptr, z, xbc, dtr);
  conv_silu<<<(M / 8) * 576 / 256, 256, 0, stream>>>(xbc, conv_w, conv_b, xc);
  dt_softplus<<<(M * NH) / 256, 256, 0, stream>>>(dtr, dt_bias, dtp);
  ssd_chunk_mfma<<<B_ * NC * NH, 256, 0, stream>>>(xc, dtp, A_log, Dv, acs, st, y);
  chunk_scan<<<(B_ * NH * HD * DSTATE) / 256, 256, 0, stream>>>(acs, st, pv);
  yoff_mfma<<<B_ * NC * NH, 256, 0, stream>>>(xc, acs, pv, y);
  gate_rmsnorm<<<M, 256, 0, stream>>>(z, norm_w, y);
  gemm_mfma<0><<<dim3(DM / 128, M / 128), 256, 0, stream>>>(
      y, wob, DI, DM, out, nullptr, nullptr, nullptr);
}

// Round 5
// 251.372 us; speedup vs baseline: 6.0047x; 1.0377x over previous
//
#include <hip/hip_runtime.h>
#include <hip/hip_bf16.h>
#include <cstdint>

typedef unsigned int  uint;
typedef unsigned short ushort;
using bf16 = __hip_bfloat16;

#define B_     4
#define T_     4096
#define DM     512
#define DI     1024
#define DSTATE 64
#define HD     64
#define NH     16
#define NC     16
#define CHK    256
#define CONVD  1152
#define DPROJ  2192

using f32x4 = __attribute__((ext_vector_type(4))) float;
using s16x8 = __attribute__((ext_vector_type(8))) short;

#define MFMA16(a, b, c) __builtin_amdgcn_mfma_f32_16x16x32_bf16((a), (b), (c), 0, 0, 0)

// ---------- bf16 helpers (bf16 = top 16 bits of fp32) ------------------------
__device__ inline void unpack8(const uint4 v, float* f) {
  const uint w[4] = {v.x, v.y, v.z, v.w};
#pragma unroll
  for (int i = 0; i < 4; ++i) {
    f[2*i]   = __uint_as_float(w[i] << 16);
    f[2*i+1] = __uint_as_float(w[i] & 0xffff0000u);
  }
}
__device__ inline void unpack4(const uint2 v, float* f) {
  f[0] = __uint_as_float(v.x << 16); f[1] = __uint_as_float(v.x & 0xffff0000u);
  f[2] = __uint_as_float(v.y << 16); f[3] = __uint_as_float(v.y & 0xffff0000u);
}
__device__ inline ushort bfbits(float a) {
  bf16 h = __float2bfloat16(a);
  return *reinterpret_cast<ushort*>(&h);
}
__device__ inline uint pack2(float a, float b) {
  return (uint)bfbits(a) | ((uint)bfbits(b) << 16);
}
__device__ inline uint4 pack8(const float* f) {
  uint4 v;
  v.x = pack2(f[0], f[1]); v.y = pack2(f[2], f[3]);
  v.z = pack2(f[4], f[5]); v.w = pack2(f[6], f[7]);
  return v;
}

// ---------- async global->LDS, 16 B per lane (wave-uniform LDS base) ---------
__device__ __forceinline__ void gl_lds16(const void* g, void* l) {
  __builtin_amdgcn_global_load_lds(
      (const __attribute__((address_space(1))) unsigned int*)g,
      (__attribute__((address_space(3))) unsigned int*)l, 16, 0, 0);
}

// ---------------- fp32 -> bf16 cast ------------------------------------------
__global__ __launch_bounds__(256)
void cast_bf16(const float* __restrict__ in, short* __restrict__ out, int n8) {
  const int i = blockIdx.x * 256 + threadIdx.x;
  if (i >= n8) return;
  float f[8];
  float4 a = *reinterpret_cast<const float4*>(&in[(size_t)i * 8]);
  float4 b = *reinterpret_cast<const float4*>(&in[(size_t)i * 8 + 4]);
  f[0]=a.x; f[1]=a.y; f[2]=a.z; f[3]=a.w; f[4]=b.x; f[5]=b.y; f[6]=b.z; f[7]=b.w;
  *reinterpret_cast<uint4*>(&out[(size_t)i * 8]) = pack8(f);
}

// ---------------- MFMA GEMM (m97 structure): C[M,N] = A[M,K] * B[N,K]^T ------
// 128x128 tile, BK=64, 4 waves (2x2), linear [128][64] LDS tiles staged with
// global_load_lds width=16 (4 issues/wave/matrix/K-step).
// EPI 0: fp32 C [M,512].  EPI 1: z/xbc bf16 via LDS-transpose + dtr f32.
template<int EPI>
__global__ __launch_bounds__(256)
void gemm_mfma(const short* __restrict__ A, const short* __restrict__ Bw,
               int K, int N, float* __restrict__ Cout,
               short* __restrict__ z, short* __restrict__ xbc,
               float* __restrict__ dtr) {
  __shared__ __align__(16) char smem[(EPI == 1) ? 34816 : 32768];
  short* As = reinterpret_cast<short*>(smem);          // [128][64] linear
  short* Bs = As + 128 * 64;                           // [128][64] linear
  const int tid  = threadIdx.x;
  const int lane = tid & 63, w = tid >> 6;
  const int hi = lane >> 4, lo = lane & 15;
  const int wr = w >> 1, wc = w & 1;
  const int bm = blockIdx.y * 128, bn = blockIdx.x * 128;

  f32x4 acc[4][4] = {};  // [lt][nt]

  // staging geometry: seg = w*4+i covers rows seg*8..seg*8+7 (1 KiB)
  const int srow = lane >> 3;          // 0..7 within segment
  const int scol = (lane & 7) * 8;     // element col (16 B granule)

  for (int k0 = 0; k0 < K; k0 += 64) {
#pragma unroll
    for (int i = 0; i < 4; ++i) {
      const int seg = w * 4 + i;
      const int row = seg * 8 + srow;
      gl_lds16(&A[(size_t)(bm + row) * K + k0 + scol], &As[seg * 512]);
      const int brow = (bn + row < N) ? (bn + row) : (N - 1);  // clamp OOB
      gl_lds16(&Bw[(size_t)brow * K + k0 + scol], &Bs[seg * 512]);
    }
    __syncthreads();
#pragma unroll
    for (int kb = 0; kb < 2; ++kb) {
      s16x8 af[4], bf[4];
#pragma unroll
      for (int t = 0; t < 4; ++t) {
        af[t] = *reinterpret_cast<const s16x8*>(&As[(wr*64 + t*16 + lo) * 64 + kb*32 + hi*8]);
        bf[t] = *reinterpret_cast<const s16x8*>(&Bs[(wc*64 + t*16 + lo) * 64 + kb*32 + hi*8]);
      }
#pragma unroll
      for (int lt = 0; lt < 4; ++lt)
#pragma unroll
        for (int nt = 0; nt < 4; ++nt)
          acc[lt][nt] = MFMA16(af[lt], bf[nt], acc[lt][nt]);
    }
    __syncthreads();
  }

  // D frag: col = lane&15 (+16nt +64wc), row = (lane>>4)*4+reg (+16lt +64wr)
  if (EPI == 0) {
#pragma unroll
    for (int lt = 0; lt < 4; ++lt)
#pragma unroll
      for (int nt = 0; nt < 4; ++nt) {
        const int cg = bn + wc * 64 + nt * 16 + lo;
#pragma unroll
        for (int r = 0; r < 4; ++r) {
          const int rg = bm + wr * 64 + lt * 16 + hi * 4 + r;
          Cout[(size_t)rg * DM + cg] = acc[lt][nt][r];
        }
      }
  } else {
    // dt columns (fp32) straight from registers
    if (bn + 128 > DI + CONVD) {
#pragma unroll
      for (int lt = 0; lt < 4; ++lt)
#pragma unroll
        for (int nt = 0; nt < 4; ++nt) {
          const int cg = bn + wc * 64 + nt * 16 + lo;
          if (cg >= DI + CONVD && cg < DPROJ) {
#pragma unroll
            for (int r = 0; r < 4; ++r) {
              const int rg = bm + wr * 64 + lt * 16 + hi * 4 + r;
              dtr[(size_t)rg * NH + (cg - DI - CONVD)] = acc[lt][nt][r];
            }
          }
        }
    }
    // bf16 z/xBC via LDS transpose -> coalesced uint4 stores
    ushort (*tile)[136] = reinterpret_cast<ushort(*)[136]>(smem);
    __syncthreads();   // staging LDS dead; safe to overwrite
#pragma unroll
    for (int lt = 0; lt < 4; ++lt)
#pragma unroll
      for (int nt = 0; nt < 4; ++nt) {
        const int cl = wc * 64 + nt * 16 + lo;
#pragma unroll
        for (int r = 0; r < 4; ++r)
          tile[wr * 64 + lt * 16 + hi * 4 + r][cl] = bfbits(acc[lt][nt][r]);
      }
    __syncthreads();
#pragma unroll
    for (int it = 0; it < 8; ++it) {
      const int unit = it * 256 + tid;      // 2048 units = 128 rows x 16 col8s
      const int row = unit >> 4;
      const int c8  = (unit & 15) << 3;
      const int cg  = bn + c8;
      const int rg  = bm + row;
      if (cg >= DI + CONVD) continue;
      uint4 v = *reinterpret_cast<const uint4*>(&tile[row][c8]);
      if (cg < DI)
        *reinterpret_cast<uint4*>(&reinterpret_cast<ushort*>(z)[(size_t)rg * DI + cg]) = v;
      else
        *reinterpret_cast<uint4*>(&reinterpret_cast<ushort*>(xbc)[(size_t)rg * CONVD + (cg - DI)]) = v;
    }
  }
}

// ---------------- causal conv(4) + SiLU --------------------------------------
// thread <-> (channel pair, 8-timestep block): coalesced loads/stores,
// vectorized float4 weight loads, taps reused in registers.
__global__ __launch_bounds__(256)
void conv_silu(const short* __restrict__ xbc, const float* __restrict__ cw,
               const float* __restrict__ cb, short* __restrict__ xc) {
  const int idx = blockIdx.x * 256 + threadIdx.x;  // (M/8) * 576
  const int cp = idx % 576;
  const int tb = idx / 576;
  const int ch = cp * 2;
  const int b  = tb >> 9;                 // T_/8 = 512 blocks per batch
  const int t0 = (tb & 511) << 3;
  const long base = ((long)b * T_ + t0) * CONVD + ch;

  const float4 wa = *reinterpret_cast<const float4*>(&cw[ch * 4]);
  const float4 wb = *reinterpret_cast<const float4*>(&cw[ch * 4 + 4]);
  const float ba = cb[ch], bb = cb[ch + 1];

  float va[11], vb[11];
#pragma unroll
  for (int i = 0; i < 11; ++i) {
    const int t = t0 - 3 + i;
    if (t >= 0) {
      const uint u = *reinterpret_cast<const uint*>(&xbc[base + (long)(i - 3) * CONVD]);
      va[i] = __uint_as_float(u << 16);
      vb[i] = __uint_as_float(u & 0xffff0000u);
    } else { va[i] = 0.f; vb[i] = 0.f; }
  }
#pragma unroll
  for (int j = 0; j < 8; ++j) {
    float sa = ba + va[j]*wa.x + va[j+1]*wa.y + va[j+2]*wa.z + va[j+3]*wa.w;
    float sb = bb + vb[j]*wb.x + vb[j+1]*wb.y + vb[j+2]*wb.z + vb[j+3]*wb.w;
    sa = sa / (1.f + __expf(-sa));
    sb = sb / (1.f + __expf(-sb));
    *reinterpret_cast<uint*>(&xc[base + (long)j * CONVD]) = pack2(sa, sb);
  }
}

// ---------------- dt softplus ------------------------------------------------
__global__ __launch_bounds__(256)
void dt_softplus(const float* __restrict__ dtr, const float* __restrict__ dt_bias,
                 float* __restrict__ dtp) {
  const int idx = blockIdx.x * 256 + threadIdx.x;  // M*NH
  const int h = idx & 15;
  const float v = dtr[idx] + dt_bias[h];
  dtp[idx] = (v > 20.f) ? v : log1pf(expf(v));
}

// ---------------- per-(b,c,h) chunk via MFMA ---------------------------------
__global__ __launch_bounds__(256, 2)
void ssd_chunk_mfma(const short* __restrict__ xc, const float* __restrict__ dtp,
                    const float* __restrict__ A_log, const float* __restrict__ Dvec,
                    float* __restrict__ acs_g, float* __restrict__ states,
                    short* __restrict__ y) {
  const int blk = blockIdx.x;
  const int h = blk & 15, c = (blk >> 4) & 15, b = blk >> 8;
  const int tid = threadIdx.x;
  const int lane = tid & 63, w = tid >> 6;
  const int hi = lane >> 4, lo = lane & 15;

  __shared__ __align__(16) float acs[CHK];
  __shared__ __align__(16) short Bsm[64][72];   // B strip [s][n]
  __shared__ __align__(16) short Btm[64][72];   // B^T     [n][s]
  __shared__ __align__(16) short Xtm[64][72];   // (x*dt)^T [p][s]
  __shared__ __align__(16) short Xdm[64][72];   // (x*dt*decay)^T [p][s]
  __shared__ __align__(16) short Pb[4][64][72]; // per-wave P [l][s]

  const size_t row0 = (size_t)b * T_ + (size_t)c * CHK;

  // cumsum of dt*A
  const float Ah = -expf(A_log[h]);
  acs[tid] = dtp[(row0 + tid) * NH + h] * Ah;
  __syncthreads();
#pragma unroll
  for (int off = 1; off < CHK; off <<= 1) {
    const float v = acs[tid];
    const float u = (tid >= off) ? acs[tid - off] : 0.f;
    __syncthreads();
    acs[tid] = v + u;
    __syncthreads();
  }
  acs_g[(((size_t)b * NH + h) * NC + c) * CHK + tid] = acs[tid];
  const float acs_last = acs[CHK - 1];

  // C strip -> registers (frag layout: row = lane&15, k = (lane>>4)*8+j)
  s16x8 creg[4][2];
#pragma unroll
  for (int lt = 0; lt < 4; ++lt)
#pragma unroll
    for (int kb = 0; kb < 2; ++kb)
      creg[lt][kb] = *reinterpret_cast<const s16x8*>(
          &xc[(row0 + w*64 + lt*16 + lo) * CONVD + DI + DSTATE + kb*32 + hi*8]);

  f32x4 yacc[4][4] = {};   // [pt][lt]
  f32x4 stacc[4]   = {};   // [nt], wave's p-strip 16w..16w+16

  const int sr = tid >> 2;        // staging row s (0..63)
  const int q  = tid & 3;         // 16-col quarter

  for (int ss = 0; ss < 4; ++ss) {
    const int s0 = ss * 64;
    // ---- stage B/Bt/Xt/Xd ----
    {
      const size_t gr = (row0 + s0 + sr) * (size_t)CONVD;
      const float dval = dtp[(row0 + s0 + sr) * NH + h];
      const float ddec = __expf(acs_last - acs[s0 + sr]);
      uint4 b0 = *reinterpret_cast<const uint4*>(&xc[gr + DI + q*16]);
      uint4 b1 = *reinterpret_cast<const uint4*>(&xc[gr + DI + q*16 + 8]);
      *reinterpret_cast<uint4*>(&Bsm[sr][q*16])     = b0;
      *reinterpret_cast<uint4*>(&Bsm[sr][q*16 + 8]) = b1;
      const short* bb0 = reinterpret_cast<const short*>(&b0);
      const short* bb1 = reinterpret_cast<const short*>(&b1);
#pragma unroll
      for (int j = 0; j < 8; ++j) Btm[q*16 + j][sr]     = bb0[j];
#pragma unroll
      for (int j = 0; j < 8; ++j) Btm[q*16 + 8 + j][sr] = bb1[j];
      uint4 x0 = *reinterpret_cast<const uint4*>(&xc[gr + h*HD + q*16]);
      uint4 x1 = *reinterpret_cast<const uint4*>(&xc[gr + h*HD + q*16 + 8]);
      float xf[16]; unpack8(x0, xf); unpack8(x1, xf + 8);
#pragma unroll
      for (int j = 0; j < 16; ++j) {
        const float xd = xf[j] * dval;
        Xtm[q*16 + j][sr] = (short)bfbits(xd);
        Xdm[q*16 + j][sr] = (short)bfbits(xd * ddec);
      }
    }
    __syncthreads();

    if (ss <= w) {   // triangular skip (wave-uniform)
      // ---- step1: S^T = B * C^T ----
      f32x4 sacc[4][4] = {};  // [lt][st]
#pragma unroll
      for (int kb = 0; kb < 2; ++kb) {
        s16x8 bfr[4];
#pragma unroll
        for (int st = 0; st < 4; ++st)
          bfr[st] = *reinterpret_cast<const s16x8*>(&Bsm[st*16 + lo][kb*32 + hi*8]);
#pragma unroll
        for (int lt = 0; lt < 4; ++lt)
#pragma unroll
          for (int st = 0; st < 4; ++st)
            sacc[lt][st] = MFMA16(bfr[st], creg[lt][kb], sacc[lt][st]);
      }
      // ---- mask+decay -> P bf16 -> LDS ----
#pragma unroll
      for (int lt = 0; lt < 4; ++lt) {
        const int l = w*64 + lt*16 + lo;
        const float al = acs[l];
#pragma unroll
        for (int st = 0; st < 4; ++st) {
          float p4[4];
#pragma unroll
          for (int r = 0; r < 4; ++r) {
            const int s = s0 + st*16 + hi*4 + r;
            const float wgt = (s <= l) ? __expf(al - acs[s]) : 0.f;
            p4[r] = sacc[lt][st][r] * wgt;
          }
          uint2 pk; pk.x = pack2(p4[0], p4[1]); pk.y = pack2(p4[2], p4[3]);
          *reinterpret_cast<uint2*>(&Pb[w][lt*16 + lo][st*16 + hi*4]) = pk;
        }
      }
      // ---- step2: Y^T += X^T * P^T ----
#pragma unroll
      for (int kb = 0; kb < 2; ++kb) {
        s16x8 xfr[4], pfr[4];
#pragma unroll
        for (int pt = 0; pt < 4; ++pt)
          xfr[pt] = *reinterpret_cast<const s16x8*>(&Xtm[pt*16 + lo][kb*32 + hi*8]);
#pragma unroll
        for (int lt = 0; lt < 4; ++lt)
          pfr[lt] = *reinterpret_cast<const s16x8*>(&Pb[w][lt*16 + lo][kb*32 + hi*8]);
#pragma unroll
        for (int pt = 0; pt < 4; ++pt)
#pragma unroll
          for (int lt = 0; lt < 4; ++lt)
            yacc[pt][lt] = MFMA16(xfr[pt], pfr[lt], yacc[pt][lt]);
      }
    }
    // ---- states += Xd * B ----
#pragma unroll
    for (int kb = 0; kb < 2; ++kb) {
      s16x8 xdf = *reinterpret_cast<const s16x8*>(&Xdm[w*16 + lo][kb*32 + hi*8]);
#pragma unroll
      for (int nt = 0; nt < 4; ++nt) {
        s16x8 btf = *reinterpret_cast<const s16x8*>(&Btm[nt*16 + lo][kb*32 + hi*8]);
        stacc[nt] = MFMA16(xdf, btf, stacc[nt]);
      }
    }
    __syncthreads();
  }

  // ---- epilogue: Y (+ D*xs) ----
  const float Dh = Dvec[h];
#pragma unroll
  for (int lt = 0; lt < 4; ++lt) {
    const int l = w*64 + lt*16 + lo;
    ushort* yrow = reinterpret_cast<ushort*>(&y[(row0 + l) * DI + h * HD]);
    const short* xrow = &xc[(row0 + l) * CONVD + h * HD];
#pragma unroll
    for (int pt = 0; pt < 4; ++pt) {
      const int p0 = pt*16 + hi*4;
      uint2 xb2 = *reinterpret_cast<const uint2*>(&xrow[p0]);
      float xf[4]; unpack4(xb2, xf);
      float o[4];
#pragma unroll
      for (int r = 0; r < 4; ++r) o[r] = yacc[pt][lt][r] + Dh * xf[r];
      uint2 pk; pk.x = pack2(o[0], o[1]); pk.y = pack2(o[2], o[3]);
      *reinterpret_cast<uint2*>(&yrow[p0]) = pk;
    }
  }
  // ---- states write (fp32) ----
  {
    const size_t sbase = (((size_t)c * B_ + b) * NH + h) * (HD * DSTATE);
#pragma unroll
    for (int nt = 0; nt < 4; ++nt) {
      const int n = nt*16 + lo;
#pragma unroll
      for (int r = 0; r < 4; ++r) {
        const int p = w*16 + hi*4 + r;
        states[sbase + (size_t)p * DSTATE + n] = stacc[nt][r];
      }
    }
  }
}

// ---------------- sequential chunk scan (prev -> bf16) -----------------------
__global__ __launch_bounds__(256)
void chunk_scan(const float* __restrict__ acs_g, const float* __restrict__ st,
                short* __restrict__ pv) {
  const int idx = blockIdx.x * 256 + threadIdx.x;  // B*NH*4096
  const int pn = idx & 4095;
  const int h  = (idx >> 12) & 15;
  const int b  = idx >> 16;
  float hst = 0.f;
#pragma unroll
  for (int c = 0; c < NC; ++c) {
    const size_t o = (((size_t)c * B_ + b) * NH + h) * 4096 + pn;
    reinterpret_cast<ushort*>(pv)[o] = bfbits(hst);
    const float dec = __expf(acs_g[(((size_t)b * NH + h) * NC + c) * CHK + CHK - 1]);
    hst = dec * hst + st[o];
  }
}

// ---------------- Y_off via MFMA: y += exp(acs_l) * C·prev^T -----------------
__global__ __launch_bounds__(256)
void yoff_mfma(const short* __restrict__ xc, const float* __restrict__ acs_g,
               const short* __restrict__ pv, short* __restrict__ y) {
  const int blk = blockIdx.x;
  const int h = blk & 15, c = (blk >> 4) & 15, b = blk >> 8;
  const int tid = threadIdx.x;
  const int lane = tid & 63, w = tid >> 6;
  const int hi = lane >> 4, lo = lane & 15;
  const size_t row0 = (size_t)b * T_ + (size_t)c * CHK;
  const float* ac = &acs_g[(((size_t)b * NH + h) * NC + c) * CHK];
  const short* pvb = &pv[(((size_t)c * B_ + b) * NH + h) * 4096];

  s16x8 creg[4][2];
#pragma unroll
  for (int lt = 0; lt < 4; ++lt)
#pragma unroll
    for (int kb = 0; kb < 2; ++kb)
      creg[lt][kb] = *reinterpret_cast<const s16x8*>(
          &xc[(row0 + w*64 + lt*16 + lo) * CONVD + DI + DSTATE + kb*32 + hi*8]);

  f32x4 acc[4][4] = {};  // [pt][lt]; D[m=p][n=l]
#pragma unroll
  for (int kb = 0; kb < 2; ++kb) {
    s16x8 pf[4];
#pragma unroll
    for (int pt = 0; pt < 4; ++pt)
      pf[pt] = *reinterpret_cast<const s16x8*>(&pvb[(pt*16 + lo) * DSTATE + kb*32 + hi*8]);
#pragma unroll
    for (int pt = 0; pt < 4; ++pt)
#pragma unroll
      for (int lt = 0; lt < 4; ++lt)
        acc[pt][lt] = MFMA16(pf[pt], creg[lt][kb], acc[pt][lt]);
  }
#pragma unroll
  for (int lt = 0; lt < 4; ++lt) {
    const int l = w*64 + lt*16 + lo;
    const float el = __expf(ac[l]);
    ushort* yrow = reinterpret_cast<ushort*>(&y[(row0 + l) * DI + h * HD]);
#pragma unroll
    for (int pt = 0; pt < 4; ++pt) {
      const int p0 = pt*16 + hi*4;
      uint2 cur = *reinterpret_cast<const uint2*>(&yrow[p0]);
      float f[4]; unpack4(cur, f);
#pragma unroll
      for (int r = 0; r < 4; ++r) f[r] += el * acc[pt][lt][r];
      uint2 pk; pk.x = pack2(f[0], f[1]); pk.y = pack2(f[2], f[3]);
      *reinterpret_cast<uint2*>(&yrow[p0]) = pk;
    }
  }
}

// ---------------- gate (silu(z)) + RMSNorm -----------------------------------
__global__ __launch_bounds__(256)
void gate_rmsnorm(const short* __restrict__ z, const float* __restrict__ norm_w,
                  short* __restrict__ y) {
  const int row = blockIdx.x;
  const int tid = threadIdx.x;
  const short* zrow = &z[(size_t)row * DI];
  short* yrow = &y[(size_t)row * DI];
  uint2 yb = *reinterpret_cast<const uint2*>(&yrow[tid * 4]);
  uint2 zb = *reinterpret_cast<const uint2*>(&zrow[tid * 4]);
  float yv[4], zv[4];
  unpack4(yb, yv); unpack4(zb, zv);
  float tq[4];
  float ss = 0.f;
#pragma unroll
  for (int j = 0; j < 4; ++j) {
    const float sil = zv[j] / (1.f + __expf(-zv[j]));
    tq[j] = yv[j] * sil;
    ss += tq[j] * tq[j];
  }
#pragma unroll
  for (int off = 32; off >= 1; off >>= 1) ss += __shfl_down(ss, off);
  __shared__ float red[4];
  if ((tid & 63) == 0) red[tid >> 6] = ss;
  __syncthreads();
  const float tot = red[0] + red[1] + red[2] + red[3];
  const float r = rsqrtf(tot * (1.f / (float)DI) + 1e-5f);
  float4 wv = *reinterpret_cast<const float4*>(&norm_w[tid * 4]);
  uint2 ob;
  ob.x = pack2(tq[0] * r * wv.x, tq[1] * r * wv.y);
  ob.y = pack2(tq[2] * r * wv.z, tq[3] * r * wv.w);
  *reinterpret_cast<uint2*>(&yrow[tid * 4]) = ob;
}

// ---------------- launcher ---------------------------------------------------
extern "C" void kernel_launch(void* const* d_in, const int* in_sizes, int n_in,
                              void* d_out, int out_size, void* d_ws, size_t ws_size,
                              hipStream_t stream) {
  const float* x       = (const float*)d_in[0];
  const float* W_in    = (const float*)d_in[1];
  const float* conv_w  = (const float*)d_in[2];
  const float* conv_b  = (const float*)d_in[3];
  const float* dt_bias = (const float*)d_in[4];
  const float* A_log   = (const float*)d_in[5];
  const float* Dv      = (const float*)d_in[6];
  const float* norm_w  = (const float*)d_in[7];
  const float* W_out   = (const float*)d_in[8];
  float* out = (float*)d_out;

  char* w0 = (char*)d_ws;
  short* z    = (short*)(w0);                    // 33,554,432 B
  short* xbc  = (short*)(w0 + 33554432ULL);      // 37,748,736 B (reused as y)
  short* xc   = (short*)(w0 + 71303168ULL);      // 37,748,736 B (xb aliases base)
  short* wob  = (short*)(w0 + 109051904ULL);     //  1,048,576 B
  float* dtr  = (float*)(w0 + 110100480ULL);     //  1,048,576 B
  float* dtp  = (float*)(w0 + 111149056ULL);     //  1,048,576 B
  float* acs  = (float*)(w0 + 112197632ULL);     //  1,048,576 B
  float* st   = (float*)(w0 + 113246208ULL);     // 16,777,216 B (wb aliases base)
  short* pv   = (short*)(w0 + 130023424ULL);     //  8,388,608 B
  short* xb   = xc;          // bf16 x: dead before conv writes xc
  short* wb   = (short*)st;  // bf16 W_in: dead before ssd writes st
  short* y    = xbc;         // y reuses xbc after conv consumes it
  // total: 138,412,032 B

  const int M = B_ * T_;  // 16384

  cast_bf16<<<(M * DM / 8 + 255) / 256, 256, 0, stream>>>(x, xb, M * DM / 8);
  cast_bf16<<<(DPROJ * DM / 8 + 255) / 256, 256, 0, stream>>>(W_in, wb, DPROJ * DM / 8);
  cast_bf16<<<(DM * DI / 8 + 255) / 256, 256, 0, stream>>>(W_out, wob, DM * DI / 8);

  gemm_mfma<1><<<dim3((DPROJ + 127) / 128, M / 128), 256, 0, stream>>>(
      xb, wb, DM, DPROJ, nullptr, z, xbc, dtr);
  conv_silu<<<(M / 8) * 576 / 256, 256, 0, stream>>>(xbc, conv_w, conv_b, xc);
  dt_softplus<<<(M * NH) / 256, 256, 0, stream>>>(dtr, dt_bias, dtp);
  ssd_chunk_mfma<<<B_ * NC * NH, 256, 0, stream>>>(xc, dtp, A_log, Dv, acs, st, y);
  chunk_scan<<<(B_ * NH * HD * DSTATE) / 256, 256, 0, stream>>>(acs, st, pv);
  yoff_mfma<<<B_ * NC * NH, 256, 0, stream>>>(xc, acs, pv, y);
  gate_rmsnorm<<<M, 256, 0, stream>>>(z, norm_w, y);
  gemm_mfma<0><<<dim3(DM / 128, M / 128), 256, 0, stream>>>(
      y, wob, DI, DM, out, nullptr, nullptr, nullptr);
}

// Round 6
// 225.529 us; speedup vs baseline: 6.6928x; 1.1146x over previous
//
#include <hip/hip_runtime.h>
#include <hip/hip_bf16.h>
#include <cstdint>

typedef unsigned int  uint;
typedef unsigned short ushort;
using bf16 = __hip_bfloat16;

#define B_     4
#define T_     4096
#define DM     512
#define DI     1024
#define DSTATE 64
#define HD     64
#define NH     16
#define NC     16
#define CHK    256
#define CONVD  1152
#define DPROJ  2192

using f32x4 = __attribute__((ext_vector_type(4))) float;
using s16x8 = __attribute__((ext_vector_type(8))) short;

#define MFMA16(a, b, c) __builtin_amdgcn_mfma_f32_16x16x32_bf16((a), (b), (c), 0, 0, 0)

// ---------- bf16 helpers (bf16 = top 16 bits of fp32) ------------------------
__device__ inline void unpack8(const uint4 v, float* f) {
  const uint w[4] = {v.x, v.y, v.z, v.w};
#pragma unroll
  for (int i = 0; i < 4; ++i) {
    f[2*i]   = __uint_as_float(w[i] << 16);
    f[2*i+1] = __uint_as_float(w[i] & 0xffff0000u);
  }
}
__device__ inline void unpack4(const uint2 v, float* f) {
  f[0] = __uint_as_float(v.x << 16); f[1] = __uint_as_float(v.x & 0xffff0000u);
  f[2] = __uint_as_float(v.y << 16); f[3] = __uint_as_float(v.y & 0xffff0000u);
}
__device__ inline ushort bfbits(float a) {
  bf16 h = __float2bfloat16(a);
  return *reinterpret_cast<ushort*>(&h);
}
__device__ inline uint pack2(float a, float b) {
  return (uint)bfbits(a) | ((uint)bfbits(b) << 16);
}
__device__ inline uint4 pack8(const float* f) {
  uint4 v;
  v.x = pack2(f[0], f[1]); v.y = pack2(f[2], f[3]);
  v.z = pack2(f[4], f[5]); v.w = pack2(f[6], f[7]);
  return v;
}

// ---------- async global->LDS, 16 B per lane (wave-uniform LDS base) ---------
__device__ __forceinline__ void gl_lds16(const void* g, void* l) {
  __builtin_amdgcn_global_load_lds(
      (const __attribute__((address_space(1))) unsigned int*)g,
      (__attribute__((address_space(3))) unsigned int*)l, 16, 0, 0);
}

// ---------------- fp32 -> bf16 cast ------------------------------------------
__global__ __launch_bounds__(256)
void cast_bf16(const float* __restrict__ in, short* __restrict__ out, int n8) {
  const int i = blockIdx.x * 256 + threadIdx.x;
  if (i >= n8) return;
  float f[8];
  float4 a = *reinterpret_cast<const float4*>(&in[(size_t)i * 8]);
  float4 b = *reinterpret_cast<const float4*>(&in[(size_t)i * 8 + 4]);
  f[0]=a.x; f[1]=a.y; f[2]=a.z; f[3]=a.w; f[4]=b.x; f[5]=b.y; f[6]=b.z; f[7]=b.w;
  *reinterpret_cast<uint4*>(&out[(size_t)i * 8]) = pack8(f);
}

// ---------------- MFMA GEMM (m97 + T1/T2): C[M,N] = A[M,K] * B[N,K]^T --------
// 128x128 tile, BK=64, 4 waves (2x2). Linear [128][64] LDS staged with
// global_load_lds width=16, XOR-swizzled: source granule g=(lane&7)^(lane>>3),
// read granule (kb*4+hi)^(lo&7)  ->  uniform 8-words/bank (conflict-free).
// 1-D grid with bijective XCD chunk swizzle (grid % 8 == 0 guaranteed).
// EPI 0: fp32 C [M,512].  EPI 1: z/xbc bf16 via LDS-transpose + dtr f32.
template<int EPI>
__global__ __launch_bounds__(256)
void gemm_mfma(const short* __restrict__ A, const short* __restrict__ Bw,
               int K, int N, int nbx, float* __restrict__ Cout,
               short* __restrict__ z, short* __restrict__ xbc,
               float* __restrict__ dtr) {
  __shared__ __align__(16) char smem[(EPI == 1) ? 34816 : 32768];
  short* As = reinterpret_cast<short*>(smem);          // [128][64] swizzled
  short* Bs = As + 128 * 64;                           // [128][64] swizzled
  const int tid  = threadIdx.x;
  const int lane = tid & 63, w = tid >> 6;
  const int hi = lane >> 4, lo = lane & 15;
  const int lx = lo & 7;
  const int wr = w >> 1, wc = w & 1;

  // XCD-aware bijective chunk swizzle (gridDim.x divisible by 8)
  const int cpx = gridDim.x >> 3;
  const int swz = (blockIdx.x & 7) * cpx + (blockIdx.x >> 3);
  const int bm = (swz / nbx) * 128, bn = (swz % nbx) * 128;

  f32x4 acc[4][4] = {};  // [lt][nt]

  // staging: seg covers rows seg*8..seg*8+7; lane row = lane>>3,
  // source granule pre-swizzled so linear LDS + swizzled read match.
  const int srow = lane >> 3;                       // 0..7 (also row&7)
  const int scol = ((lane & 7) ^ srow) * 8;         // element col of 16B granule

  for (int k0 = 0; k0 < K; k0 += 64) {
#pragma unroll
    for (int i = 0; i < 4; ++i) {
      const int seg = w * 4 + i;
      const int row = seg * 8 + srow;
      gl_lds16(&A[(size_t)(bm + row) * K + k0 + scol], &As[seg * 512]);
      const int brow = (bn + row < N) ? (bn + row) : (N - 1);  // clamp OOB
      gl_lds16(&Bw[(size_t)brow * K + k0 + scol], &Bs[seg * 512]);
    }
    __syncthreads();
#pragma unroll
    for (int kb = 0; kb < 2; ++kb) {
      s16x8 af[4], bf[4];
#pragma unroll
      for (int t = 0; t < 4; ++t) {
        const int gg = ((kb * 4 + hi) ^ lx) * 8;
        af[t] = *reinterpret_cast<const s16x8*>(&As[(wr*64 + t*16 + lo) * 64 + gg]);
        bf[t] = *reinterpret_cast<const s16x8*>(&Bs[(wc*64 + t*16 + lo) * 64 + gg]);
      }
#pragma unroll
      for (int lt = 0; lt < 4; ++lt)
#pragma unroll
        for (int nt = 0; nt < 4; ++nt)
          acc[lt][nt] = MFMA16(af[lt], bf[nt], acc[lt][nt]);
    }
    __syncthreads();
  }

  // D frag: col = lane&15 (+16nt +64wc), row = (lane>>4)*4+reg (+16lt +64wr)
  if (EPI == 0) {
#pragma unroll
    for (int lt = 0; lt < 4; ++lt)
#pragma unroll
      for (int nt = 0; nt < 4; ++nt) {
        const int cg = bn + wc * 64 + nt * 16 + lo;
#pragma unroll
        for (int r = 0; r < 4; ++r) {
          const int rg = bm + wr * 64 + lt * 16 + hi * 4 + r;
          Cout[(size_t)rg * DM + cg] = acc[lt][nt][r];
        }
      }
  } else {
    // dt columns (fp32) straight from registers
    if (bn + 128 > DI + CONVD) {
#pragma unroll
      for (int lt = 0; lt < 4; ++lt)
#pragma unroll
        for (int nt = 0; nt < 4; ++nt) {
          const int cg = bn + wc * 64 + nt * 16 + lo;
          if (cg >= DI + CONVD && cg < DPROJ) {
#pragma unroll
            for (int r = 0; r < 4; ++r) {
              const int rg = bm + wr * 64 + lt * 16 + hi * 4 + r;
              dtr[(size_t)rg * NH + (cg - DI - CONVD)] = acc[lt][nt][r];
            }
          }
        }
    }
    // bf16 z/xBC via LDS transpose -> coalesced uint4 stores
    ushort (*tile)[136] = reinterpret_cast<ushort(*)[136]>(smem);
    __syncthreads();   // staging LDS dead; safe to overwrite
#pragma unroll
    for (int lt = 0; lt < 4; ++lt)
#pragma unroll
      for (int nt = 0; nt < 4; ++nt) {
        const int cl = wc * 64 + nt * 16 + lo;
#pragma unroll
        for (int r = 0; r < 4; ++r)
          tile[wr * 64 + lt * 16 + hi * 4 + r][cl] = bfbits(acc[lt][nt][r]);
      }
    __syncthreads();
#pragma unroll
    for (int it = 0; it < 8; ++it) {
      const int unit = it * 256 + tid;      // 2048 units = 128 rows x 16 col8s
      const int row = unit >> 4;
      const int c8  = (unit & 15) << 3;
      const int cg  = bn + c8;
      const int rg  = bm + row;
      if (cg >= DI + CONVD) continue;
      uint4 v = *reinterpret_cast<const uint4*>(&tile[row][c8]);
      if (cg < DI)
        *reinterpret_cast<uint4*>(&reinterpret_cast<ushort*>(z)[(size_t)rg * DI + cg]) = v;
      else
        *reinterpret_cast<uint4*>(&reinterpret_cast<ushort*>(xbc)[(size_t)rg * CONVD + (cg - DI)]) = v;
    }
  }
}

// ---------------- causal conv(4) + SiLU --------------------------------------
__global__ __launch_bounds__(256)
void conv_silu(const short* __restrict__ xbc, const float* __restrict__ cw,
               const float* __restrict__ cb, short* __restrict__ xc) {
  const int idx = blockIdx.x * 256 + threadIdx.x;  // (M/8) * 576
  const int cp = idx % 576;
  const int tb = idx / 576;
  const int ch = cp * 2;
  const int b  = tb >> 9;                 // T_/8 = 512 blocks per batch
  const int t0 = (tb & 511) << 3;
  const long base = ((long)b * T_ + t0) * CONVD + ch;

  const float4 wa = *reinterpret_cast<const float4*>(&cw[ch * 4]);
  const float4 wb = *reinterpret_cast<const float4*>(&cw[ch * 4 + 4]);
  const float ba = cb[ch], bb = cb[ch + 1];

  float va[11], vb[11];
#pragma unroll
  for (int i = 0; i < 11; ++i) {
    const int t = t0 - 3 + i;
    if (t >= 0) {
      const uint u = *reinterpret_cast<const uint*>(&xbc[base + (long)(i - 3) * CONVD]);
      va[i] = __uint_as_float(u << 16);
      vb[i] = __uint_as_float(u & 0xffff0000u);
    } else { va[i] = 0.f; vb[i] = 0.f; }
  }
#pragma unroll
  for (int j = 0; j < 8; ++j) {
    float sa = ba + va[j]*wa.x + va[j+1]*wa.y + va[j+2]*wa.z + va[j+3]*wa.w;
    float sb = bb + vb[j]*wb.x + vb[j+1]*wb.y + vb[j+2]*wb.z + vb[j+3]*wb.w;
    sa = sa / (1.f + __expf(-sa));
    sb = sb / (1.f + __expf(-sb));
    *reinterpret_cast<uint*>(&xc[base + (long)j * CONVD]) = pack2(sa, sb);
  }
}

// ---------------- dt softplus ------------------------------------------------
__global__ __launch_bounds__(256)
void dt_softplus(const float* __restrict__ dtr, const float* __restrict__ dt_bias,
                 float* __restrict__ dtp) {
  const int idx = blockIdx.x * 256 + threadIdx.x;  // M*NH
  const int h = idx & 15;
  const float v = dtr[idx] + dt_bias[h];
  dtp[idx] = (v > 20.f) ? v : log1pf(expf(v));
}

// ---------------- per-(b,c,h) chunk via MFMA ---------------------------------
__global__ __launch_bounds__(256, 2)
void ssd_chunk_mfma(const short* __restrict__ xc, const float* __restrict__ dtp,
                    const float* __restrict__ A_log, const float* __restrict__ Dvec,
                    float* __restrict__ acs_g, float* __restrict__ states,
                    short* __restrict__ y) {
  const int blk = blockIdx.x;
  const int h = blk & 15, c = (blk >> 4) & 15, b = blk >> 8;
  const int tid = threadIdx.x;
  const int lane = tid & 63, w = tid >> 6;
  const int hi = lane >> 4, lo = lane & 15;

  __shared__ __align__(16) float acs[CHK];
  __shared__ __align__(16) short Bsm[64][72];   // B strip [s][n]
  __shared__ __align__(16) short Btm[64][72];   // B^T     [n][s]
  __shared__ __align__(16) short Xtm[64][72];   // (x*dt)^T [p][s]
  __shared__ __align__(16) short Xdm[64][72];   // (x*dt*decay)^T [p][s]
  __shared__ __align__(16) short Pb[4][64][72]; // per-wave P [l][s]

  const size_t row0 = (size_t)b * T_ + (size_t)c * CHK;

  // cumsum of dt*A
  const float Ah = -expf(A_log[h]);
  acs[tid] = dtp[(row0 + tid) * NH + h] * Ah;
  __syncthreads();
#pragma unroll
  for (int off = 1; off < CHK; off <<= 1) {
    const float v = acs[tid];
    const float u = (tid >= off) ? acs[tid - off] : 0.f;
    __syncthreads();
    acs[tid] = v + u;
    __syncthreads();
  }
  acs_g[(((size_t)b * NH + h) * NC + c) * CHK + tid] = acs[tid];
  const float acs_last = acs[CHK - 1];

  // C strip -> registers (frag layout: row = lane&15, k = (lane>>4)*8+j)
  s16x8 creg[4][2];
#pragma unroll
  for (int lt = 0; lt < 4; ++lt)
#pragma unroll
    for (int kb = 0; kb < 2; ++kb)
      creg[lt][kb] = *reinterpret_cast<const s16x8*>(
          &xc[(row0 + w*64 + lt*16 + lo) * CONVD + DI + DSTATE + kb*32 + hi*8]);

  f32x4 yacc[4][4] = {};   // [pt][lt]
  f32x4 stacc[4]   = {};   // [nt], wave's p-strip 16w..16w+16

  const int sr = tid >> 2;        // staging row s (0..63)
  const int q  = tid & 3;         // 16-col quarter

  for (int ss = 0; ss < 4; ++ss) {
    const int s0 = ss * 64;
    // ---- stage B/Bt/Xt/Xd ----
    {
      const size_t gr = (row0 + s0 + sr) * (size_t)CONVD;
      const float dval = dtp[(row0 + s0 + sr) * NH + h];
      const float ddec = __expf(acs_last - acs[s0 + sr]);
      uint4 b0 = *reinterpret_cast<const uint4*>(&xc[gr + DI + q*16]);
      uint4 b1 = *reinterpret_cast<const uint4*>(&xc[gr + DI + q*16 + 8]);
      *reinterpret_cast<uint4*>(&Bsm[sr][q*16])     = b0;
      *reinterpret_cast<uint4*>(&Bsm[sr][q*16 + 8]) = b1;
      const short* bb0 = reinterpret_cast<const short*>(&b0);
      const short* bb1 = reinterpret_cast<const short*>(&b1);
#pragma unroll
      for (int j = 0; j < 8; ++j) Btm[q*16 + j][sr]     = bb0[j];
#pragma unroll
      for (int j = 0; j < 8; ++j) Btm[q*16 + 8 + j][sr] = bb1[j];
      uint4 x0 = *reinterpret_cast<const uint4*>(&xc[gr + h*HD + q*16]);
      uint4 x1 = *reinterpret_cast<const uint4*>(&xc[gr + h*HD + q*16 + 8]);
      float xf[16]; unpack8(x0, xf); unpack8(x1, xf + 8);
#pragma unroll
      for (int j = 0; j < 16; ++j) {
        const float xd = xf[j] * dval;
        Xtm[q*16 + j][sr] = (short)bfbits(xd);
        Xdm[q*16 + j][sr] = (short)bfbits(xd * ddec);
      }
    }
    __syncthreads();

    if (ss <= w) {   // triangular skip (wave-uniform)
      // ---- step1: S^T = B * C^T ----
      f32x4 sacc[4][4] = {};  // [lt][st]
#pragma unroll
      for (int kb = 0; kb < 2; ++kb) {
        s16x8 bfr[4];
#pragma unroll
        for (int st = 0; st < 4; ++st)
          bfr[st] = *reinterpret_cast<const s16x8*>(&Bsm[st*16 + lo][kb*32 + hi*8]);
#pragma unroll
        for (int lt = 0; lt < 4; ++lt)
#pragma unroll
          for (int st = 0; st < 4; ++st)
            sacc[lt][st] = MFMA16(bfr[st], creg[lt][kb], sacc[lt][st]);
      }
      // ---- mask+decay -> P bf16 -> LDS ----
#pragma unroll
      for (int lt = 0; lt < 4; ++lt) {
        const int l = w*64 + lt*16 + lo;
        const float al = acs[l];
#pragma unroll
        for (int st = 0; st < 4; ++st) {
          float p4[4];
#pragma unroll
          for (int r = 0; r < 4; ++r) {
            const int s = s0 + st*16 + hi*4 + r;
            const float wgt = (s <= l) ? __expf(al - acs[s]) : 0.f;
            p4[r] = sacc[lt][st][r] * wgt;
          }
          uint2 pk; pk.x = pack2(p4[0], p4[1]); pk.y = pack2(p4[2], p4[3]);
          *reinterpret_cast<uint2*>(&Pb[w][lt*16 + lo][st*16 + hi*4]) = pk;
        }
      }
      // ---- step2: Y^T += X^T * P^T ----
#pragma unroll
      for (int kb = 0; kb < 2; ++kb) {
        s16x8 xfr[4], pfr[4];
#pragma unroll
        for (int pt = 0; pt < 4; ++pt)
          xfr[pt] = *reinterpret_cast<const s16x8*>(&Xtm[pt*16 + lo][kb*32 + hi*8]);
#pragma unroll
        for (int lt = 0; lt < 4; ++lt)
          pfr[lt] = *reinterpret_cast<const s16x8*>(&Pb[w][lt*16 + lo][kb*32 + hi*8]);
#pragma unroll
        for (int pt = 0; pt < 4; ++pt)
#pragma unroll
          for (int lt = 0; lt < 4; ++lt)
            yacc[pt][lt] = MFMA16(xfr[pt], pfr[lt], yacc[pt][lt]);
      }
    }
    // ---- states += Xd * B ----
#pragma unroll
    for (int kb = 0; kb < 2; ++kb) {
      s16x8 xdf = *reinterpret_cast<const s16x8*>(&Xdm[w*16 + lo][kb*32 + hi*8]);
#pragma unroll
      for (int nt = 0; nt < 4; ++nt) {
        s16x8 btf = *reinterpret_cast<const s16x8*>(&Btm[nt*16 + lo][kb*32 + hi*8]);
        stacc[nt] = MFMA16(xdf, btf, stacc[nt]);
      }
    }
    __syncthreads();
  }

  // ---- epilogue: Y (+ D*xs) ----
  const float Dh = Dvec[h];
#pragma unroll
  for (int lt = 0; lt < 4; ++lt) {
    const int l = w*64 + lt*16 + lo;
    ushort* yrow = reinterpret_cast<ushort*>(&y[(row0 + l) * DI + h * HD]);
    const short* xrow = &xc[(row0 + l) * CONVD + h * HD];
#pragma unroll
    for (int pt = 0; pt < 4; ++pt) {
      const int p0 = pt*16 + hi*4;
      uint2 xb2 = *reinterpret_cast<const uint2*>(&xrow[p0]);
      float xf[4]; unpack4(xb2, xf);
      float o[4];
#pragma unroll
      for (int r = 0; r < 4; ++r) o[r] = yacc[pt][lt][r] + Dh * xf[r];
      uint2 pk; pk.x = pack2(o[0], o[1]); pk.y = pack2(o[2], o[3]);
      *reinterpret_cast<uint2*>(&yrow[p0]) = pk;
    }
  }
  // ---- states write (fp32) ----
  {
    const size_t sbase = (((size_t)c * B_ + b) * NH + h) * (HD * DSTATE);
#pragma unroll
    for (int nt = 0; nt < 4; ++nt) {
      const int n = nt*16 + lo;
#pragma unroll
      for (int r = 0; r < 4; ++r) {
        const int p = w*16 + hi*4 + r;
        states[sbase + (size_t)p * DSTATE + n] = stacc[nt][r];
      }
    }
  }
}

// ---------------- sequential chunk scan (prev -> bf16) -----------------------
__global__ __launch_bounds__(256)
void chunk_scan(const float* __restrict__ acs_g, const float* __restrict__ st,
                short* __restrict__ pv) {
  const int idx = blockIdx.x * 256 + threadIdx.x;  // B*NH*4096
  const int pn = idx & 4095;
  const int h  = (idx >> 12) & 15;
  const int b  = idx >> 16;
  float hst = 0.f;
#pragma unroll
  for (int c = 0; c < NC; ++c) {
    const size_t o = (((size_t)c * B_ + b) * NH + h) * 4096 + pn;
    reinterpret_cast<ushort*>(pv)[o] = bfbits(hst);
    const float dec = __expf(acs_g[(((size_t)b * NH + h) * NC + c) * CHK + CHK - 1]);
    hst = dec * hst + st[o];
  }
}

// ---------------- Y_off via MFMA: y += exp(acs_l) * C·prev^T -----------------
__global__ __launch_bounds__(256)
void yoff_mfma(const short* __restrict__ xc, const float* __restrict__ acs_g,
               const short* __restrict__ pv, short* __restrict__ y) {
  const int blk = blockIdx.x;
  const int h = blk & 15, c = (blk >> 4) & 15, b = blk >> 8;
  const int tid = threadIdx.x;
  const int lane = tid & 63, w = tid >> 6;
  const int hi = lane >> 4, lo = lane & 15;
  const size_t row0 = (size_t)b * T_ + (size_t)c * CHK;
  const float* ac = &acs_g[(((size_t)b * NH + h) * NC + c) * CHK];
  const short* pvb = &pv[(((size_t)c * B_ + b) * NH + h) * 4096];

  s16x8 creg[4][2];
#pragma unroll
  for (int lt = 0; lt < 4; ++lt)
#pragma unroll
    for (int kb = 0; kb < 2; ++kb)
      creg[lt][kb] = *reinterpret_cast<const s16x8*>(
          &xc[(row0 + w*64 + lt*16 + lo) * CONVD + DI + DSTATE + kb*32 + hi*8]);

  f32x4 acc[4][4] = {};  // [pt][lt]; D[m=p][n=l]
#pragma unroll
  for (int kb = 0; kb < 2; ++kb) {
    s16x8 pf[4];
#pragma unroll
    for (int pt = 0; pt < 4; ++pt)
      pf[pt] = *reinterpret_cast<const s16x8*>(&pvb[(pt*16 + lo) * DSTATE + kb*32 + hi*8]);
#pragma unroll
    for (int pt = 0; pt < 4; ++pt)
#pragma unroll
      for (int lt = 0; lt < 4; ++lt)
        acc[pt][lt] = MFMA16(pf[pt], creg[lt][kb], acc[pt][lt]);
  }
#pragma unroll
  for (int lt = 0; lt < 4; ++lt) {
    const int l = w*64 + lt*16 + lo;
    const float el = __expf(ac[l]);
    ushort* yrow = reinterpret_cast<ushort*>(&y[(row0 + l) * DI + h * HD]);
#pragma unroll
    for (int pt = 0; pt < 4; ++pt) {
      const int p0 = pt*16 + hi*4;
      uint2 cur = *reinterpret_cast<const uint2*>(&yrow[p0]);
      float f[4]; unpack4(cur, f);
#pragma unroll
      for (int r = 0; r < 4; ++r) f[r] += el * acc[pt][lt][r];
      uint2 pk; pk.x = pack2(f[0], f[1]); pk.y = pack2(f[2], f[3]);
      *reinterpret_cast<uint2*>(&yrow[p0]) = pk;
    }
  }
}

// ---------------- gate (silu(z)) + RMSNorm -----------------------------------
__global__ __launch_bounds__(256)
void gate_rmsnorm(const short* __restrict__ z, const float* __restrict__ norm_w,
                  short* __restrict__ y) {
  const int row = blockIdx.x;
  const int tid = threadIdx.x;
  const short* zrow = &z[(size_t)row * DI];
  short* yrow = &y[(size_t)row * DI];
  uint2 yb = *reinterpret_cast<const uint2*>(&yrow[tid * 4]);
  uint2 zb = *reinterpret_cast<const uint2*>(&zrow[tid * 4]);
  float yv[4], zv[4];
  unpack4(yb, yv); unpack4(zb, zv);
  float tq[4];
  float ss = 0.f;
#pragma unroll
  for (int j = 0; j < 4; ++j) {
    const float sil = zv[j] / (1.f + __expf(-zv[j]));
    tq[j] = yv[j] * sil;
    ss += tq[j] * tq[j];
  }
#pragma unroll
  for (int off = 32; off >= 1; off >>= 1) ss += __shfl_down(ss, off);
  __shared__ float red[4];
  if ((tid & 63) == 0) red[tid >> 6] = ss;
  __syncthreads();
  const float tot = red[0] + red[1] + red[2] + red[3];
  const float r = rsqrtf(tot * (1.f / (float)DI) + 1e-5f);
  float4 wv = *reinterpret_cast<const float4*>(&norm_w[tid * 4]);
  uint2 ob;
  ob.x = pack2(tq[0] * r * wv.x, tq[1] * r * wv.y);
  ob.y = pack2(tq[2] * r * wv.z, tq[3] * r * wv.w);
  *reinterpret_cast<uint2*>(&yrow[tid * 4]) = ob;
}

// ---------------- launcher ---------------------------------------------------
extern "C" void kernel_launch(void* const* d_in, const int* in_sizes, int n_in,
                              void* d_out, int out_size, void* d_ws, size_t ws_size,
                              hipStream_t stream) {
  const float* x       = (const float*)d_in[0];
  const float* W_in    = (const float*)d_in[1];
  const float* conv_w  = (const float*)d_in[2];
  const float* conv_b  = (const float*)d_in[3];
  const float* dt_bias = (const float*)d_in[4];
  const float* A_log   = (const float*)d_in[5];
  const float* Dv      = (const float*)d_in[6];
  const float* norm_w  = (const float*)d_in[7];
  const float* W_out   = (const float*)d_in[8];
  float* out = (float*)d_out;

  char* w0 = (char*)d_ws;
  short* z    = (short*)(w0);                    // 33,554,432 B
  short* xbc  = (short*)(w0 + 33554432ULL);      // 37,748,736 B (reused as y)
  short* xc   = (short*)(w0 + 71303168ULL);      // 37,748,736 B (xb aliases base)
  short* wob  = (short*)(w0 + 109051904ULL);     //  1,048,576 B
  float* dtr  = (float*)(w0 + 110100480ULL);     //  1,048,576 B
  float* dtp  = (float*)(w0 + 111149056ULL);     //  1,048,576 B
  float* acs  = (float*)(w0 + 112197632ULL);     //  1,048,576 B
  float* st   = (float*)(w0 + 113246208ULL);     // 16,777,216 B (wb aliases base)
  short* pv   = (short*)(w0 + 130023424ULL);     //  8,388,608 B
  short* xb   = xc;          // bf16 x: dead before conv writes xc
  short* wb   = (short*)st;  // bf16 W_in: dead before ssd writes st
  short* y    = xbc;         // y reuses xbc after conv consumes it
  // total: 138,412,032 B

  const int M = B_ * T_;  // 16384

  cast_bf16<<<(M * DM / 8 + 255) / 256, 256, 0, stream>>>(x, xb, M * DM / 8);
  cast_bf16<<<(DPROJ * DM / 8 + 255) / 256, 256, 0, stream>>>(W_in, wb, DPROJ * DM / 8);
  cast_bf16<<<(DM * DI / 8 + 255) / 256, 256, 0, stream>>>(W_out, wob, DM * DI / 8);

  const int nbx_in = (DPROJ + 127) / 128;          // 18
  gemm_mfma<1><<<nbx_in * (M / 128), 256, 0, stream>>>(
      xb, wb, DM, DPROJ, nbx_in, nullptr, z, xbc, dtr);
  conv_silu<<<(M / 8) * 576 / 256, 256, 0, stream>>>(xbc, conv_w, conv_b, xc);
  dt_softplus<<<(M * NH) / 256, 256, 0, stream>>>(dtr, dt_bias, dtp);
  ssd_chunk_mfma<<<B_ * NC * NH, 256, 0, stream>>>(xc, dtp, A_log, Dv, acs, st, y);
  chunk_scan<<<(B_ * NH * HD * DSTATE) / 256, 256, 0, stream>>>(acs, st, pv);
  yoff_mfma<<<B_ * NC * NH, 256, 0, stream>>>(xc, acs, pv, y);
  gate_rmsnorm<<<M, 256, 0, stream>>>(z, norm_w, y);
  gemm_mfma<0><<<(DM / 128) * (M / 128), 256, 0, stream>>>(
      y, wob, DI, DM, DM / 128, out, nullptr, nullptr, nullptr);
}